// Round 22
// baseline (104.151 us; speedup 1.0000x reference)
//
#include <hip/hip_runtime.h>
#include <math.h>

#define BETA 0.9f
#define THR 1.0f

constexpr int B_ = 64, T_ = 256, F_ = 1024, H_ = 512;
constexpr int M_ = B_ * T_;  // 16384 rows

typedef float f32x4 __attribute__((ext_vector_type(4)));
typedef short short8 __attribute__((ext_vector_type(8)));
typedef _Float16 half8 __attribute__((ext_vector_type(8)));
typedef unsigned short us4 __attribute__((ext_vector_type(4)));
typedef unsigned short us8 __attribute__((ext_vector_type(8)));
typedef unsigned short ushort_t;

// ---- bf16 helpers (RNE) ----------------------------------------------------
static __device__ __forceinline__ unsigned short f2bf(float x) {
    unsigned b = __builtin_bit_cast(unsigned, x);
    unsigned r = (b + 0x7FFFu + ((b >> 16) & 1u)) >> 16;
    return (unsigned short)r;
}
static __device__ __forceinline__ float bf2f(unsigned short u) {
    unsigned v = ((unsigned)u) << 16;
    return __builtin_bit_cast(float, v);
}
// ---- f16 helpers ------------------------------------------------------------
static __device__ __forceinline__ unsigned short f2h(float x) {
    _Float16 h = (_Float16)x;
    return __builtin_bit_cast(unsigned short, h);
}
static __device__ __forceinline__ float h2f(unsigned short u) {
    return (float)__builtin_bit_cast(_Float16, u);
}
// BK=32 swizzle (64B rows, 4 chunks) — used by prep only.
static __device__ __forceinline__ int swz(int r) {
    return ((r >> 2) & 3) ^ (r & 3);
}

#define GLDS(srcp, dstp)                                                      \
    __builtin_amdgcn_global_load_lds(                                         \
        (const __attribute__((address_space(1))) unsigned int*)(srcp),        \
        (__attribute__((address_space(3))) unsigned int*)(dstp), 16, 0, 0)

// ---------------------------------------------------------------------------
// Fused f16 GEMM + leaky scan — 128N tile, 16 waves, DEPTH-2 prefetch.
// R21 (128N, 2-phase dbuf) = 103.8us best; already 1 block/CU, so the
// third buffer (144KB LDS) costs no occupancy. Loads for tile t+2 issue at
// iter t; pre-barrier COUNTED s_waitcnt keeps tile-(t+1) loads in flight
// (T4; R19's failure was the 2->1 blk/CU drop, absent here).
// FIFO per wave: AF32=0: 3 GLDS/iter (A:2,B:1) -> vmcnt(3) (last: 0).
// AF32=1: writeA32's areg wait drains older GLDS; only current stageB
// outstanding -> vmcnt(1) lgkmcnt(0) (last: 0).
// Wave w: rows (w>>1)*32..+31, cols (w&1)*64..+63. Grid (4,64)=256 wgs;
// clip-grouped XCD map clip=((flat>>5)<<3)|(flat&7), strip=(flat>>3)&3.
// LDS 3 x 24576 ushorts (A 32 segs + B 16 segs per buffer). Involution
// pos = c ^ (r&7). Scan spill reuses [0,33280) — safe: post-loop
// __syncthreads() fully drains before reuse.
// ---------------------------------------------------------------------------
template <int AF32>
__global__ __launch_bounds__(1024, 1) void gemm_scan(
    const void* __restrict__ Asrc, const ushort_t* __restrict__ Bp,
    const float* __restrict__ bias, ushort_t* __restrict__ Sout, int K) {
    constexpr int BUF = 24576;  // ushorts per buffer (48KB)
    __shared__ ushort_t lds[3 * BUF];  // 144KB

    const int tid = threadIdx.x;
    const int w = tid >> 6, l = tid & 63;  // 16 waves
    const int flat = blockIdx.y * gridDim.x + blockIdx.x;
    const int clip = ((flat >> 5) << 3) | (flat & 7);  // [0,64)
    const int strip = (flat >> 3) & 3;                 // [0,4)
    const int n0 = strip * 128;
    const int m0 = clip * 256;
    const int wr = w >> 1, wc = w & 1;

    f32x4 acc[2][4];
#pragma unroll
    for (int mi = 0; mi < 2; ++mi)
#pragma unroll
        for (int ni = 0; ni < 4; ++ni) acc[mi][ni] = (f32x4){0.f, 0.f, 0.f, 0.f};

    const int c0 = l >> 4;
    const int schunk = (l & 7) ^ ((l >> 3) & 7);  // pre-swizzled source chunk

    // AF32 staging state: 2 row-chunks of 8 f32 (2 f32x4 each) per thread.
    f32x4 areg[2][2];

    auto stageB = [&](int buf, int k0) {
        // B tile 128x64 f16 = 16KB = 16 segs; 1 per wave
        const int r = w * 8 + (l >> 3);
        GLDS(Bp + (size_t)(n0 + r) * K + k0 + schunk * 8,
             &lds[buf + 16384 + w * 512]);
    };
    auto stageA16 = [&](int buf, int k0) {
        // A tile 256x64 f16 = 32KB = 32 segs; 2 per wave
#pragma unroll
        for (int j = 0; j < 2; ++j) {
            const int seg = w * 2 + j;  // 0..31
            const int r = seg * 8 + (l >> 3);
            GLDS((const ushort_t*)Asrc + (size_t)(m0 + r) * K + k0 + schunk * 8,
                 &lds[buf + seg * 512]);
        }
    };
    auto loadA32 = [&](int k0) {  // 256x64 f32: 16 f32/thread, 8 lanes/row
#pragma unroll
        for (int j = 0; j < 2; ++j) {
            const int r = j * 128 + (tid >> 3);
            const float* src =
                (const float*)Asrc + (size_t)(m0 + r) * K + k0 + (tid & 7) * 8;
            areg[j][0] = *(const f32x4*)src;
            areg[j][1] = *(const f32x4*)(src + 4);
        }
    };
    auto writeA32 = [&](int buf) {  // convert + swizzled 16B ds_write
#pragma unroll
        for (int j = 0; j < 2; ++j) {
            const int r = j * 128 + (tid >> 3);
            us8 hv;
#pragma unroll
            for (int e = 0; e < 4; ++e) {
                hv[e] = f2h(areg[j][0][e]);
                hv[e + 4] = f2h(areg[j][1][e]);
            }
            const int pos = (tid & 7) ^ (r & 7);
            *(us8*)&lds[buf + r * 64 + pos * 8] = hv;
        }
    };

    const int nt = K / 64;
    // prologue: fill buffers 0 and 1 (depth-2)
    if constexpr (AF32) {
        loadA32(0);
        writeA32(0);          // compiler drains areg loads here
        loadA32(64);
        writeA32(BUF);
        stageB(0, 0);
        stageB(BUF, 64);
    } else {
        stageA16(0, 0);       // A then B per tile: FIFO order uniform
        stageB(0, 0);
        stageA16(BUF, 64);
        stageB(BUF, 64);
    }

    for (int t = 0; t < nt; ++t) {
        const int cur = (t % 3) * BUF;
        const int n2 = ((t + 2) % 3) * BUF;
        const bool pre = (t + 2 < nt);
        // counted pre-barrier wait: keep tile-(t+1) loads in flight
        if constexpr (AF32) {
            if (t + 1 < nt)
                asm volatile("s_waitcnt vmcnt(1) lgkmcnt(0)" ::: "memory");
            else
                asm volatile("s_waitcnt vmcnt(0) lgkmcnt(0)" ::: "memory");
        } else {
            if (t + 1 < nt)
                asm volatile("s_waitcnt vmcnt(3)" ::: "memory");
            else
                asm volatile("s_waitcnt vmcnt(0)" ::: "memory");
        }
        __builtin_amdgcn_s_barrier();
        __builtin_amdgcn_sched_barrier(0);  // pin ds_reads below (rule #18)

        if (pre) {
            if constexpr (AF32) {
                loadA32((t + 2) * 64);
                stageB(n2, (t + 2) * 64);
            } else {
                stageA16(n2, (t + 2) * 64);
                stageB(n2, (t + 2) * 64);
            }
        }

#pragma unroll
        for (int kh = 0; kh < 2; ++kh) {
            half8 aa[2], bb[4];
            const int q = kh * 4 + c0;
#pragma unroll
            for (int mi = 0; mi < 2; ++mi) {
                const int r = wr * 32 + mi * 16 + (l & 15);
                const int off = cur + r * 64 + ((q ^ (l & 7)) * 8);
                aa[mi] = __builtin_bit_cast(half8, *(const short8*)&lds[off]);
            }
#pragma unroll
            for (int ni = 0; ni < 4; ++ni) {
                const int r = wc * 64 + ni * 16 + (l & 15);
                const int off = cur + 16384 + r * 64 + ((q ^ (l & 7)) * 8);
                bb[ni] = __builtin_bit_cast(half8, *(const short8*)&lds[off]);
            }
            __builtin_amdgcn_s_setprio(1);
#pragma unroll
            for (int mi = 0; mi < 2; ++mi)
#pragma unroll
                for (int ni = 0; ni < 4; ++ni)
                    acc[mi][ni] = __builtin_amdgcn_mfma_f32_16x16x32_f16(
                        aa[mi], bb[ni], acc[mi][ni], 0, 0, 0);
            __builtin_amdgcn_s_setprio(0);
        }

        if constexpr (AF32) {
            if (pre) writeA32(n2);  // write-late; compiler waits areg loads
        }
    }

    __syncthreads();  // full drain: ALL frag reads complete, LDS dead

    // acc(+bias) -> LDS x[t][h] f16, stride 130 (65 dwords: bank-spread)
    float bv[4];
#pragma unroll
    for (int ni = 0; ni < 4; ++ni)
        bv[ni] = bias[n0 + wc * 64 + ni * 16 + (l & 15)];
#pragma unroll
    for (int mi = 0; mi < 2; ++mi) {
        const int t0 = wr * 32 + mi * 16 + ((l >> 4) << 2);
#pragma unroll
        for (int ni = 0; ni < 4; ++ni) {
            const int h = wc * 64 + ni * 16 + (l & 15);
#pragma unroll
            for (int r = 0; r < 4; ++r)
                lds[(t0 + r) * 130 + h] = f2h(acc[mi][ni][r] + bv[ni]);
        }
    }
    __syncthreads();

    // scan: threads 0..127 each own one h column; snntorch Leaky subtract
    if (tid < 128) {
        const int h = tid;
        ushort_t* sp = Sout + (size_t)m0 * 512 + n0 + h;
        float m = 0.f;
#pragma unroll 4
        for (int t = 0; t < T_; ++t) {
            const float xv = h2f(lds[t * 130 + h]);
            const float r = (m - THR > 0.f) ? THR : 0.f;
            m = BETA * m + xv - r;
            sp[(size_t)t * 512] = (m - THR > 0.f) ? (ushort_t)0x3C00 : (ushort_t)0;
        }
    }
}

// ---------------------------------------------------------------------------
// f16 MFMA GEMM, BK=64, 2-phase double-buffered, fused MIL head epilogue:
// p = relu(C+bias) dot u over this wave's 64-col strip -> part[strip][row].
// Tile 128x128, 4 waves (2x2). Grid (4, 128) = 512 wgs, m-grouped XCD map.
// LDS 64KB = 2 x 16384 ushorts; 2 blocks/CU. T5 setprio on MFMA cluster.
// ---------------------------------------------------------------------------
__global__ __launch_bounds__(256) void gemm_mil(
    const ushort_t* __restrict__ Ap, const ushort_t* __restrict__ Bp,
    const float* __restrict__ bias, const float* __restrict__ Uv,
    float* __restrict__ part, int N, int K) {
    constexpr int BUF = 16384;  // ushorts per buffer (32KB)
    __shared__ ushort_t lds[2 * BUF];

    const int tid = threadIdx.x;
    const int w = tid >> 6, l = tid & 63;
    const int flat = blockIdx.y * gridDim.x + blockIdx.x;
    const int mt = ((flat >> 5) << 3) | (flat & 7);
    const int st = (flat >> 3) & 3;
    const int n0 = st * 128;
    const int m0 = mt * 128;
    const int wr = w >> 1, wc = w & 1;

    f32x4 acc[4][4];
#pragma unroll
    for (int mi = 0; mi < 4; ++mi)
#pragma unroll
        for (int ni = 0; ni < 4; ++ni) acc[mi][ni] = (f32x4){0.f, 0.f, 0.f, 0.f};

    const int c0 = l >> 4;
    const int schunk = (l & 7) ^ ((l >> 3) & 7);

    auto stage = [&](int buf, int k0) {
#pragma unroll
        for (int j = 0; j < 8; ++j) {
            const int g = w * 8 + j;  // 0..31
            const int seg = g & 15;
            const int r = seg * 8 + (l >> 3);
            const ushort_t* pl = (g < 16) ? Ap : Bp;
            const int rb = (g < 16) ? m0 : n0;
            GLDS(pl + (size_t)(rb + r) * K + k0 + schunk * 8,
                 &lds[buf + g * 512]);
        }
    };

    const int nt = K / 64;
    stage(0, 0);
    for (int t = 0; t < nt; ++t) {
        const int cur = (t & 1) * BUF;
        const int nxt = BUF - cur;
        __syncthreads();
        if (t + 1 < nt) stage(nxt, (t + 1) * 64);

#pragma unroll
        for (int kh = 0; kh < 2; ++kh) {
            half8 aa[4], bb[4];
            const int q = kh * 4 + c0;
#pragma unroll
            for (int mi = 0; mi < 4; ++mi) {
                const int r = wr * 64 + mi * 16 + (l & 15);
                const int off = cur + r * 64 + ((q ^ (l & 7)) * 8);
                aa[mi] = __builtin_bit_cast(half8, *(const short8*)&lds[off]);
            }
#pragma unroll
            for (int ni = 0; ni < 4; ++ni) {
                const int r = wc * 64 + ni * 16 + (l & 15);
                const int off = cur + 8192 + r * 64 + ((q ^ (l & 7)) * 8);
                bb[ni] = __builtin_bit_cast(half8, *(const short8*)&lds[off]);
            }
            __builtin_amdgcn_s_setprio(1);
#pragma unroll
            for (int mi = 0; mi < 4; ++mi)
#pragma unroll
                for (int ni = 0; ni < 4; ++ni)
                    acc[mi][ni] = __builtin_amdgcn_mfma_f32_16x16x32_f16(
                        aa[mi], bb[ni], acc[mi][ni], 0, 0, 0);
            __builtin_amdgcn_s_setprio(0);
        }
    }

    // fused MIL: per row partial = sum_col relu(acc+bias)*u[col]
    float bv[4], uc[4];
#pragma unroll
    for (int ni = 0; ni < 4; ++ni) {
        const int col = n0 + wc * 64 + ni * 16 + (l & 15);
        bv[ni] = bias[col];
        uc[ni] = Uv[col];
    }
    const int strip = (n0 >> 6) + wc;  // 0..7
#pragma unroll
    for (int mi = 0; mi < 4; ++mi) {
        float p[4];
#pragma unroll
        for (int r = 0; r < 4; ++r) {
            float s = 0.f;
#pragma unroll
            for (int ni = 0; ni < 4; ++ni)
                s += fmaxf(acc[mi][ni][r] + bv[ni], 0.f) * uc[ni];
            p[r] = s;
        }
#pragma unroll
        for (int off = 1; off <= 8; off <<= 1)
#pragma unroll
            for (int r = 0; r < 4; ++r) p[r] += __shfl_xor(p[r], off);
        if ((l & 15) == 0) {
            const int row0 = m0 + wr * 64 + mi * 16 + ((l >> 4) << 2);
#pragma unroll
            for (int r = 0; r < 4; ++r)
                part[(size_t)strip * M_ + row0 + r] = p[r];
        }
    }
}

// ---------------------------------------------------------------------------
// Split-bf16 3-product GEMM for Wc = W1 @ Wf, BK=64 + dbuf.
// Tile 128x128, 4 waves (2x2). Grid (8,4)=32 wgs. LDS 128KB = 2 x 32768
// ushorts (Ah/Al/Bh/Bl 16 segs each per buffer). Emits single f16 plane.
// ---------------------------------------------------------------------------
__global__ __launch_bounds__(256, 1) void gemm_bf16_wc(
    const ushort_t* __restrict__ Ah, const ushort_t* __restrict__ Al,
    const ushort_t* __restrict__ Bh, const ushort_t* __restrict__ Bl,
    ushort_t* __restrict__ Cout, int N, int K) {
    constexpr int BUF = 32768;  // ushorts per buffer (64KB)
    __shared__ ushort_t lds[2 * BUF];

    const int tid = threadIdx.x;
    const int w = tid >> 6, l = tid & 63;
    const int flat = blockIdx.y * gridDim.x + blockIdx.x;
    const int n0 = (flat % gridDim.x) * 128;
    const int m0 = (flat / gridDim.x) * 128;
    const int wr = w >> 1, wc = w & 1;

    f32x4 acc[4][4];
#pragma unroll
    for (int mi = 0; mi < 4; ++mi)
#pragma unroll
        for (int ni = 0; ni < 4; ++ni) acc[mi][ni] = (f32x4){0.f, 0.f, 0.f, 0.f};

    const int c0 = l >> 4;
    const int schunk = (l & 7) ^ ((l >> 3) & 7);

    auto stage = [&](int buf, int k0) {
        // 64 segs of 1KB: Ah 0-15, Al 16-31, Bh 32-47, Bl 48-63; 16/wave
#pragma unroll
        for (int j = 0; j < 16; ++j) {
            const int g = w * 16 + j;
            const int p = g >> 4, seg = g & 15;
            const int r = seg * 8 + (l >> 3);
            const ushort_t* pl = (p == 0) ? Ah : (p == 1) ? Al : (p == 2) ? Bh : Bl;
            const int rb = (p < 2) ? m0 : n0;
            GLDS(pl + (size_t)(rb + r) * K + k0 + schunk * 8,
                 &lds[buf + g * 512]);
        }
    };

    const int nt = K / 64;
    stage(0, 0);
    for (int t = 0; t < nt; ++t) {
        const int cur = (t & 1) * BUF;
        const int nxt = BUF - cur;
        __syncthreads();
        if (t + 1 < nt) stage(nxt, (t + 1) * 64);

#pragma unroll
        for (int kh = 0; kh < 2; ++kh) {
            short8 ah[4], al[4], bh[4], bl[4];
            const int q = kh * 4 + c0;
#pragma unroll
            for (int mi = 0; mi < 4; ++mi) {
                const int r = wr * 64 + mi * 16 + (l & 15);
                const int off = r * 64 + ((q ^ (l & 7)) * 8);
                ah[mi] = *(const short8*)&lds[cur + off];
                al[mi] = *(const short8*)&lds[cur + 8192 + off];
            }
#pragma unroll
            for (int ni = 0; ni < 4; ++ni) {
                const int r = wc * 64 + ni * 16 + (l & 15);
                const int off = r * 64 + ((q ^ (l & 7)) * 8);
                bh[ni] = *(const short8*)&lds[cur + 16384 + off];
                bl[ni] = *(const short8*)&lds[cur + 24576 + off];
            }
            __builtin_amdgcn_s_setprio(1);
#pragma unroll
            for (int mi = 0; mi < 4; ++mi)
#pragma unroll
                for (int ni = 0; ni < 4; ++ni) {
                    acc[mi][ni] = __builtin_amdgcn_mfma_f32_16x16x32_bf16(
                        ah[mi], bh[ni], acc[mi][ni], 0, 0, 0);
                    acc[mi][ni] = __builtin_amdgcn_mfma_f32_16x16x32_bf16(
                        ah[mi], bl[ni], acc[mi][ni], 0, 0, 0);
                    acc[mi][ni] = __builtin_amdgcn_mfma_f32_16x16x32_bf16(
                        al[mi], bh[ni], acc[mi][ni], 0, 0, 0);
                }
            __builtin_amdgcn_s_setprio(0);
        }
    }

#pragma unroll
    for (int ni = 0; ni < 4; ++ni) {
        const int col = n0 + wc * 64 + ni * 16 + (l & 15);
#pragma unroll
        for (int mi = 0; mi < 4; ++mi) {
            const int row0 = m0 + wr * 64 + mi * 16 + ((l >> 4) << 2);
#pragma unroll
            for (int r = 0; r < 4; ++r)
                Cout[(size_t)(row0 + r) * N + col] = f2h(acc[mi][ni][r]);
        }
    }
}

// ---------------------------------------------------------------------------
// Sectioned prep (one launch, 1410 blocks):
//   [0,256):      W1 -> bf16 hi/lo planes
//   [256,512):    W2 -> f16
//   [512,768):    Mw1 -> f16
//   [768,896):    bc[j] = b1[j] + W1[j,:]@bf  (wave per j)
//   [896,898):    u[j] = Mw3@Mw2[:,j]; uc[512] = Mw3@Mb2+Mb3
//   [898,1410):   Wf -> WfT bf16 hi/lo planes (32x32 transpose tiles)
// ---------------------------------------------------------------------------
__global__ __launch_bounds__(256) void prep_small(
    const float* __restrict__ W1, const float* __restrict__ W2,
    const float* __restrict__ Mw1, const float* __restrict__ bfv,
    const float* __restrict__ b1, const float* __restrict__ Mw2,
    const float* __restrict__ Mb2, const float* __restrict__ Mw3,
    const float* __restrict__ Mb3, const float* __restrict__ Wf,
    ushort_t* __restrict__ w1h, ushort_t* __restrict__ w1l,
    ushort_t* __restrict__ w2f, ushort_t* __restrict__ m1f,
    float* __restrict__ bc, float* __restrict__ uc,
    ushort_t* __restrict__ wfTh, ushort_t* __restrict__ wfTl) {
    __shared__ float tile[32][33];
    const int blk = blockIdx.x;
    const int tid = threadIdx.x;
    if (blk < 256) {
        const int i = blk * 256 + tid;
        f32x4 v = ((const f32x4*)W1)[i];
        us4 h, ll;
#pragma unroll
        for (int e = 0; e < 4; ++e) {
            const unsigned short hb = f2bf(v[e]);
            h[e] = hb;
            ll[e] = f2bf(v[e] - bf2f(hb));
        }
        ((us4*)w1h)[i] = h;
        ((us4*)w1l)[i] = ll;
    } else if (blk < 512) {
        const int i = (blk - 256) * 256 + tid;
        f32x4 v = ((const f32x4*)W2)[i];
        us4 h;
#pragma unroll
        for (int e = 0; e < 4; ++e) h[e] = f2h(v[e]);
        ((us4*)w2f)[i] = h;
    } else if (blk < 768) {
        const int i = (blk - 512) * 256 + tid;
        f32x4 v = ((const f32x4*)Mw1)[i];
        us4 h;
#pragma unroll
        for (int e = 0; e < 4; ++e) h[e] = f2h(v[e]);
        ((us4*)m1f)[i] = h;
    } else if (blk < 896) {
        const int w = tid >> 6, l = tid & 63;
        const int j = (blk - 768) * 4 + w;
        const float* row = W1 + (size_t)j * 512;
        float a = 0.f;
#pragma unroll
        for (int i = 0; i < 8; ++i) a += row[l + i * 64] * bfv[l + i * 64];
#pragma unroll
        for (int off = 32; off >= 1; off >>= 1) a += __shfl_xor(a, off);
        if (l == 0) bc[j] = a + b1[j];
    } else if (blk < 898) {
        const int j = (blk - 896) * 256 + tid;  // 0..511
        float a = 0.f;
        for (int i = 0; i < 32; ++i) a += Mw3[i] * Mw2[(size_t)i * 512 + j];
        uc[j] = a;
        if (j == 0) {
            float c = Mb3[0];
            for (int i = 0; i < 32; ++i) c += Mw3[i] * Mb2[i];
            uc[512] = c;
        }
    } else {
        const int idx = blk - 898;          // 0..511
        const int k0 = (idx & 31) * 32;     // Wf col tile
        const int i0 = (idx >> 5) * 32;     // Wf row tile
        const int tx = tid & 31;
        const int ty = tid >> 5;  // 0..7
#pragma unroll
        for (int e = 0; e < 4; ++e) {
            const int i = ty + e * 8;
            tile[i][tx] = Wf[(size_t)(i0 + i) * 1024 + k0 + tx];
        }
        __syncthreads();
#pragma unroll
        for (int e = 0; e < 4; ++e) {
            const int kk = ty + e * 8;
            const float v = tile[tx][kk];
            const unsigned short h = f2bf(v);
            wfTh[(size_t)(k0 + kk) * 512 + i0 + tx] = h;
            wfTl[(size_t)(k0 + kk) * 512 + i0 + tx] = f2bf(v - bf2f(h));
        }
    }
}

// ---------------------------------------------------------------------------
// Tail: pre[row] = sum_{s<8} part[s][row] + c; top-17 on pre (sigmoid
// monotonic), mean of sigmoid(selected). One wave per clip.
// ---------------------------------------------------------------------------
__global__ __launch_bounds__(64) void tail_topk(const float* __restrict__ part,
                                                const float* __restrict__ uc,
                                                float* __restrict__ out) {
    const int b = blockIdx.x;
    const int lane = threadIdx.x;
    const float c = uc[512];
    float v[4];
#pragma unroll
    for (int i = 0; i < 4; ++i) {
        const int row = b * T_ + lane + i * 64;
        float a = 0.f;
#pragma unroll
        for (int s = 0; s < 8; ++s) a += part[(size_t)s * M_ + row];
        v[i] = a + c;
    }
    float sum = 0.f;
    for (int iter = 0; iter < 17; ++iter) {
        float mv = v[0];
        int mslot = 0;
#pragma unroll
        for (int i = 1; i < 4; ++i)
            if (v[i] > mv) { mv = v[i]; mslot = i; }
        float bv = mv;
        int bl = lane, bs = mslot;
#pragma unroll
        for (int off = 32; off >= 1; off >>= 1) {
            const float ov = __shfl_xor(bv, off);
            const int ol = __shfl_xor(bl, off);
            const int os = __shfl_xor(bs, off);
            if (ov > bv || (ov == bv && ol < bl)) { bv = ov; bl = ol; bs = os; }
        }
        sum += 1.f / (1.f + expf(-bv));
        if (lane == bl) v[bs] = -1e30f;
    }
    if (lane == 0) out[b] = sum * (1.f / 17.f);
}

// ---------------------------------------------------------------------------
// Orchestration (6 launches):
//   prep_small (weights + Wf transpose)
//   wcf   <- gemm_bf16_wc(W1 planes @ WfT^T)      [BK=64 dbuf]
//   sbuf1 <- gemm_scan<1>(f_f(f32) @ wcf^T + bc)  [128N, depth-2 prefetch]
//   sbuf2 <- gemm_scan<0>(sbuf1 @ w2f^T + b2)     [128N, depth-2 prefetch]
//   part  <- gemm_mil(sbuf2 @ m1f^T + Mb1)        [MIL fused]
//   out   <- tail_topk(part)
// ---------------------------------------------------------------------------
extern "C" void kernel_launch(void* const* d_in, const int* in_sizes, int n_in,
                              void* d_out, int out_size, void* d_ws, size_t ws_size,
                              hipStream_t stream) {
    const float* f_f = (const float*)d_in[0];
    const float* Wf  = (const float*)d_in[2];
    const float* bf  = (const float*)d_in[3];
    const float* W1  = (const float*)d_in[4];
    const float* b1  = (const float*)d_in[5];
    const float* W2  = (const float*)d_in[6];
    const float* b2  = (const float*)d_in[7];
    const float* Mw1 = (const float*)d_in[8];
    const float* Mb1 = (const float*)d_in[9];
    const float* Mw2 = (const float*)d_in[10];
    const float* Mb2 = (const float*)d_in[11];
    const float* Mw3 = (const float*)d_in[12];
    const float* Mb3 = (const float*)d_in[13];
    float* out = (float*)d_out;

    char* ws = (char*)d_ws;
    const size_t NE = (size_t)M_ * H_;   // 8.39M elems
    ushort_t* sbuf1 = (ushort_t*)ws;                     // f16 spikes 1
    ushort_t* sbuf2 = sbuf1 + NE;                        // f16 spikes 2
    ushort_t* w1h = sbuf2 + NE;                          // bf16 (wc input)
    ushort_t* w1l = w1h + 262144;
    ushort_t* w2f = w1l + 262144;                        // f16 single
    ushort_t* m1f = w2f + 262144;                        // f16 single
    ushort_t* wfTh = m1f + 262144;                       // bf16 [1024,512]
    ushort_t* wfTl = wfTh + 524288;
    ushort_t* wcf = wfTl + 524288;                       // f16 [512,1024]
    float* bc = (float*)(wcf + 524288);
    float* uc = bc + 512;                                // u[512] + c
    float* part = uc + 513 + 63;                         // [8][16384] f32

    const dim3 blk(256);

    prep_small<<<dim3(1410), blk, 0, stream>>>(W1, W2, Mw1, bf, b1, Mw2, Mb2,
                                               Mw3, Mb3, Wf, w1h, w1l, w2f,
                                               m1f, bc, uc, wfTh, wfTl);

    // Wc = W1 @ Wf -> f16 [512,1024]
    gemm_bf16_wc<<<dim3(8, 4), blk, 0, stream>>>(w1h, w1l, wfTh, wfTl, wcf,
                                                 1024, 512);
    // x1 = f_f @ Wc^T + bc, fused scan1 -> sbuf1 (f32 A, in-kernel convert)
    gemm_scan<1><<<dim3(4, 64), dim3(1024), 0, stream>>>(f_f, wcf, bc, sbuf1,
                                                         1024);
    // x2 = sbuf1 @ W2^T + b2, fused scan2 -> sbuf2
    gemm_scan<0><<<dim3(4, 64), dim3(1024), 0, stream>>>(sbuf1, w2f, b2, sbuf2,
                                                         512);
    // z-GEMM with fused MIL head -> part[8][M]
    gemm_mil<<<dim3(4, 128), blk, 0, stream>>>(sbuf2, m1f, Mb1, uc, part,
                                               512, 512);
    tail_topk<<<dim3(B_), dim3(64), 0, stream>>>(part, uc, out);
}

// Round 23
// 103.821 us; speedup vs baseline: 1.0032x; 1.0032x over previous
//
#include <hip/hip_runtime.h>
#include <math.h>

#define BETA 0.9f
#define THR 1.0f

constexpr int B_ = 64, T_ = 256, F_ = 1024, H_ = 512;
constexpr int M_ = B_ * T_;  // 16384 rows

typedef float f32x4 __attribute__((ext_vector_type(4)));
typedef short short8 __attribute__((ext_vector_type(8)));
typedef _Float16 half8 __attribute__((ext_vector_type(8)));
typedef unsigned short us4 __attribute__((ext_vector_type(4)));
typedef unsigned short us8 __attribute__((ext_vector_type(8)));
typedef unsigned short ushort_t;

// ---- bf16 helpers (RNE) ----------------------------------------------------
static __device__ __forceinline__ unsigned short f2bf(float x) {
    unsigned b = __builtin_bit_cast(unsigned, x);
    unsigned r = (b + 0x7FFFu + ((b >> 16) & 1u)) >> 16;
    return (unsigned short)r;
}
static __device__ __forceinline__ float bf2f(unsigned short u) {
    unsigned v = ((unsigned)u) << 16;
    return __builtin_bit_cast(float, v);
}
// ---- f16 helpers ------------------------------------------------------------
static __device__ __forceinline__ unsigned short f2h(float x) {
    _Float16 h = (_Float16)x;
    return __builtin_bit_cast(unsigned short, h);
}
static __device__ __forceinline__ float h2f(unsigned short u) {
    return (float)__builtin_bit_cast(_Float16, u);
}
// BK=32 swizzle (64B rows, 4 chunks) — used by prep only.
static __device__ __forceinline__ int swz(int r) {
    return ((r >> 2) & 3) ^ (r & 3);
}

#define GLDS(srcp, dstp)                                                      \
    __builtin_amdgcn_global_load_lds(                                         \
        (const __attribute__((address_space(1))) unsigned int*)(srcp),        \
        (__attribute__((address_space(3))) unsigned int*)(dstp), 16, 0, 0)

// ---------------------------------------------------------------------------
// Fused f16 GEMM + leaky scan — FINAL CONFIG (R21 = best of 23 rounds).
// 128-wide N-tile, 16 waves (1024 threads), BK=64, 2-phase dbuf.
// R22 post-mortem: depth-2 counted-vmcnt was null (within noise) — third
// confirmation that counted-prefetch without full 8-phase interleave
// doesn't pay; reverted to the simpler 2-buffer form.
// AF32=0: A f16 staged via GLDS (pre-swizzled). AF32=1: A f32 (f_f direct),
// reg-load + convert f2h + swizzled ds_write after MFMA (write-late).
// Wave w: rows (w>>1)*32..+31, cols (w&1)*64..+63 (2 m-frags x 4 n-frags).
// Grid (4 strips, 64 clips) = 256 wgs = 1/CU; clip-grouped XCD map
// clip=((flat>>5)<<3)|(flat&7) (bijective), strip=(flat>>3)&3.
// LDS: BUF=24576 ushorts/buffer (A 32 segs @ [0,16384), B 16 segs @
// [16384,24576)). Involution pos = c ^ (r&7) (128B rows, 8x16B chunks).
// Scan buffer 256x130 ushorts (65-dword stride, bank-spread) at [0,33280);
// safe: pre-spill __syncthreads() completes all frag reads first.
// ---------------------------------------------------------------------------
template <int AF32>
__global__ __launch_bounds__(1024, 1) void gemm_scan(
    const void* __restrict__ Asrc, const ushort_t* __restrict__ Bp,
    const float* __restrict__ bias, ushort_t* __restrict__ Sout, int K) {
    constexpr int BUF = 24576;  // ushorts per buffer (48KB)
    __shared__ ushort_t lds[2 * BUF];  // 96KB

    const int tid = threadIdx.x;
    const int w = tid >> 6, l = tid & 63;  // 16 waves
    const int flat = blockIdx.y * gridDim.x + blockIdx.x;
    const int clip = ((flat >> 5) << 3) | (flat & 7);  // [0,64)
    const int strip = (flat >> 3) & 3;                 // [0,4)
    const int n0 = strip * 128;
    const int m0 = clip * 256;
    const int wr = w >> 1, wc = w & 1;

    f32x4 acc[2][4];
#pragma unroll
    for (int mi = 0; mi < 2; ++mi)
#pragma unroll
        for (int ni = 0; ni < 4; ++ni) acc[mi][ni] = (f32x4){0.f, 0.f, 0.f, 0.f};

    const int c0 = l >> 4;
    const int schunk = (l & 7) ^ ((l >> 3) & 7);  // pre-swizzled source chunk

    // AF32 staging state: 2 row-chunks of 8 f32 (2 f32x4 each) per thread.
    f32x4 areg[2][2];

    auto stageB = [&](int buf, int k0) {
        // B tile 128x64 f16 = 16KB = 16 segs; 1 per wave
        const int r = w * 8 + (l >> 3);
        GLDS(Bp + (size_t)(n0 + r) * K + k0 + schunk * 8,
             &lds[buf + 16384 + w * 512]);
    };
    auto stageA16 = [&](int buf, int k0) {
        // A tile 256x64 f16 = 32KB = 32 segs; 2 per wave
#pragma unroll
        for (int j = 0; j < 2; ++j) {
            const int seg = w * 2 + j;  // 0..31
            const int r = seg * 8 + (l >> 3);
            GLDS((const ushort_t*)Asrc + (size_t)(m0 + r) * K + k0 + schunk * 8,
                 &lds[buf + seg * 512]);
        }
    };
    auto loadA32 = [&](int k0) {  // 256x64 f32: 16 f32/thread, 8 lanes/row
#pragma unroll
        for (int j = 0; j < 2; ++j) {
            const int r = j * 128 + (tid >> 3);
            const float* src =
                (const float*)Asrc + (size_t)(m0 + r) * K + k0 + (tid & 7) * 8;
            areg[j][0] = *(const f32x4*)src;
            areg[j][1] = *(const f32x4*)(src + 4);
        }
    };
    auto writeA32 = [&](int buf) {  // convert + swizzled 16B ds_write
#pragma unroll
        for (int j = 0; j < 2; ++j) {
            const int r = j * 128 + (tid >> 3);
            us8 hv;
#pragma unroll
            for (int e = 0; e < 4; ++e) {
                hv[e] = f2h(areg[j][0][e]);
                hv[e + 4] = f2h(areg[j][1][e]);
            }
            const int pos = (tid & 7) ^ (r & 7);
            *(us8*)&lds[buf + r * 64 + pos * 8] = hv;
        }
    };

    const int nt = K / 64;
    // prologue: fill buffer 0
    if constexpr (AF32) {
        loadA32(0);
        writeA32(0);
    } else {
        stageA16(0, 0);
    }
    stageB(0, 0);

    for (int t = 0; t < nt; ++t) {
        const int cur = (t & 1) * BUF;
        const int nxt = BUF - cur;
        __syncthreads();  // drains stage(t); protects buffer reuse
        const bool more = (t + 1 < nt);
        if (more) {
            if constexpr (AF32) {
                loadA32((t + 1) * 64);
                stageB(nxt, (t + 1) * 64);
            } else {
                stageA16(nxt, (t + 1) * 64);
                stageB(nxt, (t + 1) * 64);
            }
        }

#pragma unroll
        for (int kh = 0; kh < 2; ++kh) {
            half8 aa[2], bb[4];
            const int q = kh * 4 + c0;
#pragma unroll
            for (int mi = 0; mi < 2; ++mi) {
                const int r = wr * 32 + mi * 16 + (l & 15);
                const int off = cur + r * 64 + ((q ^ (l & 7)) * 8);
                aa[mi] = __builtin_bit_cast(half8, *(const short8*)&lds[off]);
            }
#pragma unroll
            for (int ni = 0; ni < 4; ++ni) {
                const int r = wc * 64 + ni * 16 + (l & 15);
                const int off = cur + 16384 + r * 64 + ((q ^ (l & 7)) * 8);
                bb[ni] = __builtin_bit_cast(half8, *(const short8*)&lds[off]);
            }
            __builtin_amdgcn_s_setprio(1);
#pragma unroll
            for (int mi = 0; mi < 2; ++mi)
#pragma unroll
                for (int ni = 0; ni < 4; ++ni)
                    acc[mi][ni] = __builtin_amdgcn_mfma_f32_16x16x32_f16(
                        aa[mi], bb[ni], acc[mi][ni], 0, 0, 0);
            __builtin_amdgcn_s_setprio(0);
        }

        if constexpr (AF32) {
            if (more) writeA32(nxt);  // write-late: after MFMA, before barrier
        }
    }

    __syncthreads();  // ALL frag reads complete before LDS reuse by the spill

    // acc(+bias) -> LDS x[t][h] f16, stride 130 (65 dwords: bank-spread)
    float bv[4];
#pragma unroll
    for (int ni = 0; ni < 4; ++ni)
        bv[ni] = bias[n0 + wc * 64 + ni * 16 + (l & 15)];
#pragma unroll
    for (int mi = 0; mi < 2; ++mi) {
        const int t0 = wr * 32 + mi * 16 + ((l >> 4) << 2);
#pragma unroll
        for (int ni = 0; ni < 4; ++ni) {
            const int h = wc * 64 + ni * 16 + (l & 15);
#pragma unroll
            for (int r = 0; r < 4; ++r)
                lds[(t0 + r) * 130 + h] = f2h(acc[mi][ni][r] + bv[ni]);
        }
    }
    __syncthreads();

    // scan: threads 0..127 each own one h column; snntorch Leaky subtract
    if (tid < 128) {
        const int h = tid;
        ushort_t* sp = Sout + (size_t)m0 * 512 + n0 + h;
        float m = 0.f;
#pragma unroll 4
        for (int t = 0; t < T_; ++t) {
            const float xv = h2f(lds[t * 130 + h]);
            const float r = (m - THR > 0.f) ? THR : 0.f;
            m = BETA * m + xv - r;
            sp[(size_t)t * 512] = (m - THR > 0.f) ? (ushort_t)0x3C00 : (ushort_t)0;
        }
    }
}

// ---------------------------------------------------------------------------
// f16 MFMA GEMM, BK=64, 2-phase double-buffered, fused MIL head epilogue:
// p = relu(C+bias) dot u over this wave's 64-col strip -> part[strip][row].
// Tile 128x128, 4 waves (2x2). Grid (4, 128) = 512 wgs, m-grouped XCD map.
// LDS 64KB = 2 x 16384 ushorts; 2 blocks/CU. T5 setprio on MFMA cluster.
// ---------------------------------------------------------------------------
__global__ __launch_bounds__(256) void gemm_mil(
    const ushort_t* __restrict__ Ap, const ushort_t* __restrict__ Bp,
    const float* __restrict__ bias, const float* __restrict__ Uv,
    float* __restrict__ part, int N, int K) {
    constexpr int BUF = 16384;  // ushorts per buffer (32KB)
    __shared__ ushort_t lds[2 * BUF];

    const int tid = threadIdx.x;
    const int w = tid >> 6, l = tid & 63;
    const int flat = blockIdx.y * gridDim.x + blockIdx.x;
    const int mt = ((flat >> 5) << 3) | (flat & 7);
    const int st = (flat >> 3) & 3;
    const int n0 = st * 128;
    const int m0 = mt * 128;
    const int wr = w >> 1, wc = w & 1;

    f32x4 acc[4][4];
#pragma unroll
    for (int mi = 0; mi < 4; ++mi)
#pragma unroll
        for (int ni = 0; ni < 4; ++ni) acc[mi][ni] = (f32x4){0.f, 0.f, 0.f, 0.f};

    const int c0 = l >> 4;
    const int schunk = (l & 7) ^ ((l >> 3) & 7);

    auto stage = [&](int buf, int k0) {
#pragma unroll
        for (int j = 0; j < 8; ++j) {
            const int g = w * 8 + j;  // 0..31
            const int seg = g & 15;
            const int r = seg * 8 + (l >> 3);
            const ushort_t* pl = (g < 16) ? Ap : Bp;
            const int rb = (g < 16) ? m0 : n0;
            GLDS(pl + (size_t)(rb + r) * K + k0 + schunk * 8,
                 &lds[buf + g * 512]);
        }
    };

    const int nt = K / 64;
    stage(0, 0);
    for (int t = 0; t < nt; ++t) {
        const int cur = (t & 1) * BUF;
        const int nxt = BUF - cur;
        __syncthreads();
        if (t + 1 < nt) stage(nxt, (t + 1) * 64);

#pragma unroll
        for (int kh = 0; kh < 2; ++kh) {
            half8 aa[4], bb[4];
            const int q = kh * 4 + c0;
#pragma unroll
            for (int mi = 0; mi < 4; ++mi) {
                const int r = wr * 64 + mi * 16 + (l & 15);
                const int off = cur + r * 64 + ((q ^ (l & 7)) * 8);
                aa[mi] = __builtin_bit_cast(half8, *(const short8*)&lds[off]);
            }
#pragma unroll
            for (int ni = 0; ni < 4; ++ni) {
                const int r = wc * 64 + ni * 16 + (l & 15);
                const int off = cur + 8192 + r * 64 + ((q ^ (l & 7)) * 8);
                bb[ni] = __builtin_bit_cast(half8, *(const short8*)&lds[off]);
            }
            __builtin_amdgcn_s_setprio(1);
#pragma unroll
            for (int mi = 0; mi < 4; ++mi)
#pragma unroll
                for (int ni = 0; ni < 4; ++ni)
                    acc[mi][ni] = __builtin_amdgcn_mfma_f32_16x16x32_f16(
                        aa[mi], bb[ni], acc[mi][ni], 0, 0, 0);
            __builtin_amdgcn_s_setprio(0);
        }
    }

    // fused MIL: per row partial = sum_col relu(acc+bias)*u[col]
    float bv[4], uc[4];
#pragma unroll
    for (int ni = 0; ni < 4; ++ni) {
        const int col = n0 + wc * 64 + ni * 16 + (l & 15);
        bv[ni] = bias[col];
        uc[ni] = Uv[col];
    }
    const int strip = (n0 >> 6) + wc;  // 0..7
#pragma unroll
    for (int mi = 0; mi < 4; ++mi) {
        float p[4];
#pragma unroll
        for (int r = 0; r < 4; ++r) {
            float s = 0.f;
#pragma unroll
            for (int ni = 0; ni < 4; ++ni)
                s += fmaxf(acc[mi][ni][r] + bv[ni], 0.f) * uc[ni];
            p[r] = s;
        }
#pragma unroll
        for (int off = 1; off <= 8; off <<= 1)
#pragma unroll
            for (int r = 0; r < 4; ++r) p[r] += __shfl_xor(p[r], off);
        if ((l & 15) == 0) {
            const int row0 = m0 + wr * 64 + mi * 16 + ((l >> 4) << 2);
#pragma unroll
            for (int r = 0; r < 4; ++r)
                part[(size_t)strip * M_ + row0 + r] = p[r];
        }
    }
}

// ---------------------------------------------------------------------------
// Split-bf16 3-product GEMM for Wc = W1 @ Wf, BK=64 + dbuf.
// Tile 128x128, 4 waves (2x2). Grid (8,4)=32 wgs. LDS 128KB = 2 x 32768
// ushorts (Ah/Al/Bh/Bl 16 segs each per buffer). Emits single f16 plane.
// ---------------------------------------------------------------------------
__global__ __launch_bounds__(256, 1) void gemm_bf16_wc(
    const ushort_t* __restrict__ Ah, const ushort_t* __restrict__ Al,
    const ushort_t* __restrict__ Bh, const ushort_t* __restrict__ Bl,
    ushort_t* __restrict__ Cout, int N, int K) {
    constexpr int BUF = 32768;  // ushorts per buffer (64KB)
    __shared__ ushort_t lds[2 * BUF];

    const int tid = threadIdx.x;
    const int w = tid >> 6, l = tid & 63;
    const int flat = blockIdx.y * gridDim.x + blockIdx.x;
    const int n0 = (flat % gridDim.x) * 128;
    const int m0 = (flat / gridDim.x) * 128;
    const int wr = w >> 1, wc = w & 1;

    f32x4 acc[4][4];
#pragma unroll
    for (int mi = 0; mi < 4; ++mi)
#pragma unroll
        for (int ni = 0; ni < 4; ++ni) acc[mi][ni] = (f32x4){0.f, 0.f, 0.f, 0.f};

    const int c0 = l >> 4;
    const int schunk = (l & 7) ^ ((l >> 3) & 7);

    auto stage = [&](int buf, int k0) {
        // 64 segs of 1KB: Ah 0-15, Al 16-31, Bh 32-47, Bl 48-63; 16/wave
#pragma unroll
        for (int j = 0; j < 16; ++j) {
            const int g = w * 16 + j;
            const int p = g >> 4, seg = g & 15;
            const int r = seg * 8 + (l >> 3);
            const ushort_t* pl = (p == 0) ? Ah : (p == 1) ? Al : (p == 2) ? Bh : Bl;
            const int rb = (p < 2) ? m0 : n0;
            GLDS(pl + (size_t)(rb + r) * K + k0 + schunk * 8,
                 &lds[buf + g * 512]);
        }
    };

    const int nt = K / 64;
    stage(0, 0);
    for (int t = 0; t < nt; ++t) {
        const int cur = (t & 1) * BUF;
        const int nxt = BUF - cur;
        __syncthreads();
        if (t + 1 < nt) stage(nxt, (t + 1) * 64);

#pragma unroll
        for (int kh = 0; kh < 2; ++kh) {
            short8 ah[4], al[4], bh[4], bl[4];
            const int q = kh * 4 + c0;
#pragma unroll
            for (int mi = 0; mi < 4; ++mi) {
                const int r = wr * 64 + mi * 16 + (l & 15);
                const int off = r * 64 + ((q ^ (l & 7)) * 8);
                ah[mi] = *(const short8*)&lds[cur + off];
                al[mi] = *(const short8*)&lds[cur + 8192 + off];
            }
#pragma unroll
            for (int ni = 0; ni < 4; ++ni) {
                const int r = wc * 64 + ni * 16 + (l & 15);
                const int off = r * 64 + ((q ^ (l & 7)) * 8);
                bh[ni] = *(const short8*)&lds[cur + 16384 + off];
                bl[ni] = *(const short8*)&lds[cur + 24576 + off];
            }
            __builtin_amdgcn_s_setprio(1);
#pragma unroll
            for (int mi = 0; mi < 4; ++mi)
#pragma unroll
                for (int ni = 0; ni < 4; ++ni) {
                    acc[mi][ni] = __builtin_amdgcn_mfma_f32_16x16x32_bf16(
                        ah[mi], bh[ni], acc[mi][ni], 0, 0, 0);
                    acc[mi][ni] = __builtin_amdgcn_mfma_f32_16x16x32_bf16(
                        ah[mi], bl[ni], acc[mi][ni], 0, 0, 0);
                    acc[mi][ni] = __builtin_amdgcn_mfma_f32_16x16x32_bf16(
                        al[mi], bh[ni], acc[mi][ni], 0, 0, 0);
                }
            __builtin_amdgcn_s_setprio(0);
        }
    }

#pragma unroll
    for (int ni = 0; ni < 4; ++ni) {
        const int col = n0 + wc * 64 + ni * 16 + (l & 15);
#pragma unroll
        for (int mi = 0; mi < 4; ++mi) {
            const int row0 = m0 + wr * 64 + mi * 16 + ((l >> 4) << 2);
#pragma unroll
            for (int r = 0; r < 4; ++r)
                Cout[(size_t)(row0 + r) * N + col] = f2h(acc[mi][ni][r]);
        }
    }
}

// ---------------------------------------------------------------------------
// Sectioned prep (one launch, 1410 blocks):
//   [0,256):      W1 -> bf16 hi/lo planes
//   [256,512):    W2 -> f16
//   [512,768):    Mw1 -> f16
//   [768,896):    bc[j] = b1[j] + W1[j,:]@bf  (wave per j)
//   [896,898):    u[j] = Mw3@Mw2[:,j]; uc[512] = Mw3@Mb2+Mb3
//   [898,1410):   Wf -> WfT bf16 hi/lo planes (32x32 transpose tiles)
// ---------------------------------------------------------------------------
__global__ __launch_bounds__(256) void prep_small(
    const float* __restrict__ W1, const float* __restrict__ W2,
    const float* __restrict__ Mw1, const float* __restrict__ bfv,
    const float* __restrict__ b1, const float* __restrict__ Mw2,
    const float* __restrict__ Mb2, const float* __restrict__ Mw3,
    const float* __restrict__ Mb3, const float* __restrict__ Wf,
    ushort_t* __restrict__ w1h, ushort_t* __restrict__ w1l,
    ushort_t* __restrict__ w2f, ushort_t* __restrict__ m1f,
    float* __restrict__ bc, float* __restrict__ uc,
    ushort_t* __restrict__ wfTh, ushort_t* __restrict__ wfTl) {
    __shared__ float tile[32][33];
    const int blk = blockIdx.x;
    const int tid = threadIdx.x;
    if (blk < 256) {
        const int i = blk * 256 + tid;
        f32x4 v = ((const f32x4*)W1)[i];
        us4 h, ll;
#pragma unroll
        for (int e = 0; e < 4; ++e) {
            const unsigned short hb = f2bf(v[e]);
            h[e] = hb;
            ll[e] = f2bf(v[e] - bf2f(hb));
        }
        ((us4*)w1h)[i] = h;
        ((us4*)w1l)[i] = ll;
    } else if (blk < 512) {
        const int i = (blk - 256) * 256 + tid;
        f32x4 v = ((const f32x4*)W2)[i];
        us4 h;
#pragma unroll
        for (int e = 0; e < 4; ++e) h[e] = f2h(v[e]);
        ((us4*)w2f)[i] = h;
    } else if (blk < 768) {
        const int i = (blk - 512) * 256 + tid;
        f32x4 v = ((const f32x4*)Mw1)[i];
        us4 h;
#pragma unroll
        for (int e = 0; e < 4; ++e) h[e] = f2h(v[e]);
        ((us4*)m1f)[i] = h;
    } else if (blk < 896) {
        const int w = tid >> 6, l = tid & 63;
        const int j = (blk - 768) * 4 + w;
        const float* row = W1 + (size_t)j * 512;
        float a = 0.f;
#pragma unroll
        for (int i = 0; i < 8; ++i) a += row[l + i * 64] * bfv[l + i * 64];
#pragma unroll
        for (int off = 32; off >= 1; off >>= 1) a += __shfl_xor(a, off);
        if (l == 0) bc[j] = a + b1[j];
    } else if (blk < 898) {
        const int j = (blk - 896) * 256 + tid;  // 0..511
        float a = 0.f;
        for (int i = 0; i < 32; ++i) a += Mw3[i] * Mw2[(size_t)i * 512 + j];
        uc[j] = a;
        if (j == 0) {
            float c = Mb3[0];
            for (int i = 0; i < 32; ++i) c += Mw3[i] * Mb2[i];
            uc[512] = c;
        }
    } else {
        const int idx = blk - 898;          // 0..511
        const int k0 = (idx & 31) * 32;     // Wf col tile
        const int i0 = (idx >> 5) * 32;     // Wf row tile
        const int tx = tid & 31;
        const int ty = tid >> 5;  // 0..7
#pragma unroll
        for (int e = 0; e < 4; ++e) {
            const int i = ty + e * 8;
            tile[i][tx] = Wf[(size_t)(i0 + i) * 1024 + k0 + tx];
        }
        __syncthreads();
#pragma unroll
        for (int e = 0; e < 4; ++e) {
            const int kk = ty + e * 8;
            const float v = tile[tx][kk];
            const unsigned short h = f2bf(v);
            wfTh[(size_t)(k0 + kk) * 512 + i0 + tx] = h;
            wfTl[(size_t)(k0 + kk) * 512 + i0 + tx] = f2bf(v - bf2f(h));
        }
    }
}

// ---------------------------------------------------------------------------
// Tail: pre[row] = sum_{s<8} part[s][row] + c; top-17 on pre (sigmoid
// monotonic), mean of sigmoid(selected). One wave per clip.
// ---------------------------------------------------------------------------
__global__ __launch_bounds__(64) void tail_topk(const float* __restrict__ part,
                                                const float* __restrict__ uc,
                                                float* __restrict__ out) {
    const int b = blockIdx.x;
    const int lane = threadIdx.x;
    const float c = uc[512];
    float v[4];
#pragma unroll
    for (int i = 0; i < 4; ++i) {
        const int row = b * T_ + lane + i * 64;
        float a = 0.f;
#pragma unroll
        for (int s = 0; s < 8; ++s) a += part[(size_t)s * M_ + row];
        v[i] = a + c;
    }
    float sum = 0.f;
    for (int iter = 0; iter < 17; ++iter) {
        float mv = v[0];
        int mslot = 0;
#pragma unroll
        for (int i = 1; i < 4; ++i)
            if (v[i] > mv) { mv = v[i]; mslot = i; }
        float bv = mv;
        int bl = lane, bs = mslot;
#pragma unroll
        for (int off = 32; off >= 1; off >>= 1) {
            const float ov = __shfl_xor(bv, off);
            const int ol = __shfl_xor(bl, off);
            const int os = __shfl_xor(bs, off);
            if (ov > bv || (ov == bv && ol < bl)) { bv = ov; bl = ol; bs = os; }
        }
        sum += 1.f / (1.f + expf(-bv));
        if (lane == bl) v[bs] = -1e30f;
    }
    if (lane == 0) out[b] = sum * (1.f / 17.f);
}

// ---------------------------------------------------------------------------
// Orchestration (6 launches):
//   prep_small (weights + Wf transpose)
//   wcf   <- gemm_bf16_wc(W1 planes @ WfT^T)      [BK=64 dbuf]
//   sbuf1 <- gemm_scan<1>(f_f(f32) @ wcf^T + bc)  [16-wave, 128N tile]
//   sbuf2 <- gemm_scan<0>(sbuf1 @ w2f^T + b2)     [16-wave, 128N tile]
//   part  <- gemm_mil(sbuf2 @ m1f^T + Mb1)        [MIL fused]
//   out   <- tail_topk(part)
// ---------------------------------------------------------------------------
extern "C" void kernel_launch(void* const* d_in, const int* in_sizes, int n_in,
                              void* d_out, int out_size, void* d_ws, size_t ws_size,
                              hipStream_t stream) {
    const float* f_f = (const float*)d_in[0];
    const float* Wf  = (const float*)d_in[2];
    const float* bf  = (const float*)d_in[3];
    const float* W1  = (const float*)d_in[4];
    const float* b1  = (const float*)d_in[5];
    const float* W2  = (const float*)d_in[6];
    const float* b2  = (const float*)d_in[7];
    const float* Mw1 = (const float*)d_in[8];
    const float* Mb1 = (const float*)d_in[9];
    const float* Mw2 = (const float*)d_in[10];
    const float* Mb2 = (const float*)d_in[11];
    const float* Mw3 = (const float*)d_in[12];
    const float* Mb3 = (const float*)d_in[13];
    float* out = (float*)d_out;

    char* ws = (char*)d_ws;
    const size_t NE = (size_t)M_ * H_;   // 8.39M elems
    ushort_t* sbuf1 = (ushort_t*)ws;                     // f16 spikes 1
    ushort_t* sbuf2 = sbuf1 + NE;                        // f16 spikes 2
    ushort_t* w1h = sbuf2 + NE;                          // bf16 (wc input)
    ushort_t* w1l = w1h + 262144;
    ushort_t* w2f = w1l + 262144;                        // f16 single
    ushort_t* m1f = w2f + 262144;                        // f16 single
    ushort_t* wfTh = m1f + 262144;                       // bf16 [1024,512]
    ushort_t* wfTl = wfTh + 524288;
    ushort_t* wcf = wfTl + 524288;                       // f16 [512,1024]
    float* bc = (float*)(wcf + 524288);
    float* uc = bc + 512;                                // u[512] + c
    float* part = uc + 513 + 63;                         // [8][16384] f32

    const dim3 blk(256);

    prep_small<<<dim3(1410), blk, 0, stream>>>(W1, W2, Mw1, bf, b1, Mw2, Mb2,
                                               Mw3, Mb3, Wf, w1h, w1l, w2f,
                                               m1f, bc, uc, wfTh, wfTl);

    // Wc = W1 @ Wf -> f16 [512,1024]
    gemm_bf16_wc<<<dim3(8, 4), blk, 0, stream>>>(w1h, w1l, wfTh, wfTl, wcf,
                                                 1024, 512);
    // x1 = f_f @ Wc^T + bc, fused scan1 -> sbuf1 (f32 A, in-kernel convert)
    gemm_scan<1><<<dim3(4, 64), dim3(1024), 0, stream>>>(f_f, wcf, bc, sbuf1,
                                                         1024);
    // x2 = sbuf1 @ W2^T + b2, fused scan2 -> sbuf2
    gemm_scan<0><<<dim3(4, 64), dim3(1024), 0, stream>>>(sbuf1, w2f, b2, sbuf2,
                                                         512);
    // z-GEMM with fused MIL head -> part[8][M]
    gemm_mil<<<dim3(4, 128), blk, 0, stream>>>(sbuf2, m1f, Mb1, uc, part,
                                               512, 512);
    tail_topk<<<dim3(B_), dim3(64), 0, stream>>>(part, uc, out);
}

// Round 24
// 103.104 us; speedup vs baseline: 1.0102x; 1.0070x over previous
//
#include <hip/hip_runtime.h>
#include <math.h>

#define BETA 0.9f
#define THR 1.0f

constexpr int B_ = 64, T_ = 256, F_ = 1024, H_ = 512;
constexpr int M_ = B_ * T_;  // 16384 rows

typedef float f32x4 __attribute__((ext_vector_type(4)));
typedef short short8 __attribute__((ext_vector_type(8)));
typedef _Float16 half8 __attribute__((ext_vector_type(8)));
typedef unsigned short us4 __attribute__((ext_vector_type(4)));
typedef unsigned short us8 __attribute__((ext_vector_type(8)));
typedef unsigned short ushort_t;

// ---- bf16 helpers (RNE) ----------------------------------------------------
static __device__ __forceinline__ unsigned short f2bf(float x) {
    unsigned b = __builtin_bit_cast(unsigned, x);
    unsigned r = (b + 0x7FFFu + ((b >> 16) & 1u)) >> 16;
    return (unsigned short)r;
}
static __device__ __forceinline__ float bf2f(unsigned short u) {
    unsigned v = ((unsigned)u) << 16;
    return __builtin_bit_cast(float, v);
}
// ---- f16 helpers ------------------------------------------------------------
static __device__ __forceinline__ unsigned short f2h(float x) {
    _Float16 h = (_Float16)x;
    return __builtin_bit_cast(unsigned short, h);
}
static __device__ __forceinline__ float h2f(unsigned short u) {
    return (float)__builtin_bit_cast(_Float16, u);
}
// BK=32 swizzle (64B rows, 4 chunks) — used by prep only.
static __device__ __forceinline__ int swz(int r) {
    return ((r >> 2) & 3) ^ (r & 3);
}

#define GLDS(srcp, dstp)                                                      \
    __builtin_amdgcn_global_load_lds(                                         \
        (const __attribute__((address_space(1))) unsigned int*)(srcp),        \
        (__attribute__((address_space(3))) unsigned int*)(dstp), 16, 0, 0)

// ---------------------------------------------------------------------------
// Fused f16 GEMM + leaky scan — FINAL CONFIG (R21/R23 best, reproduced 3x).
// 128-wide N-tile, 16 waves (1024 threads), BK=64, 2-phase dbuf.
// AF32=0: A f16 staged via GLDS (pre-swizzled). AF32=1: A f32 (f_f direct),
// reg-load + convert f2h + swizzled ds_write after MFMA (write-late).
// Wave w: rows (w>>1)*32..+31, cols (w&1)*64..+63 (2 m-frags x 4 n-frags).
// Grid (4 strips, 64 clips) = 256 wgs = 1/CU; clip-grouped XCD map
// clip=((flat>>5)<<3)|(flat&7) (bijective), strip=(flat>>3)&3.
// LDS: BUF=24576 ushorts/buffer (A 32 segs @ [0,16384), B 16 segs @
// [16384,24576)). Involution pos = c ^ (r&7) (128B rows, 8x16B chunks).
// Scan buffer 256x130 ushorts (65-dword stride, bank-spread) at [0,33280);
// safe: pre-spill __syncthreads() completes all frag reads first.
// ---------------------------------------------------------------------------
template <int AF32>
__global__ __launch_bounds__(1024, 1) void gemm_scan(
    const void* __restrict__ Asrc, const ushort_t* __restrict__ Bp,
    const float* __restrict__ bias, ushort_t* __restrict__ Sout, int K) {
    constexpr int BUF = 24576;  // ushorts per buffer (48KB)
    __shared__ ushort_t lds[2 * BUF];  // 96KB

    const int tid = threadIdx.x;
    const int w = tid >> 6, l = tid & 63;  // 16 waves
    const int flat = blockIdx.y * gridDim.x + blockIdx.x;
    const int clip = ((flat >> 5) << 3) | (flat & 7);  // [0,64)
    const int strip = (flat >> 3) & 3;                 // [0,4)
    const int n0 = strip * 128;
    const int m0 = clip * 256;
    const int wr = w >> 1, wc = w & 1;

    f32x4 acc[2][4];
#pragma unroll
    for (int mi = 0; mi < 2; ++mi)
#pragma unroll
        for (int ni = 0; ni < 4; ++ni) acc[mi][ni] = (f32x4){0.f, 0.f, 0.f, 0.f};

    const int c0 = l >> 4;
    const int schunk = (l & 7) ^ ((l >> 3) & 7);  // pre-swizzled source chunk

    // AF32 staging state: 2 row-chunks of 8 f32 (2 f32x4 each) per thread.
    f32x4 areg[2][2];

    auto stageB = [&](int buf, int k0) {
        // B tile 128x64 f16 = 16KB = 16 segs; 1 per wave
        const int r = w * 8 + (l >> 3);
        GLDS(Bp + (size_t)(n0 + r) * K + k0 + schunk * 8,
             &lds[buf + 16384 + w * 512]);
    };
    auto stageA16 = [&](int buf, int k0) {
        // A tile 256x64 f16 = 32KB = 32 segs; 2 per wave
#pragma unroll
        for (int j = 0; j < 2; ++j) {
            const int seg = w * 2 + j;  // 0..31
            const int r = seg * 8 + (l >> 3);
            GLDS((const ushort_t*)Asrc + (size_t)(m0 + r) * K + k0 + schunk * 8,
                 &lds[buf + seg * 512]);
        }
    };
    auto loadA32 = [&](int k0) {  // 256x64 f32: 16 f32/thread, 8 lanes/row
#pragma unroll
        for (int j = 0; j < 2; ++j) {
            const int r = j * 128 + (tid >> 3);
            const float* src =
                (const float*)Asrc + (size_t)(m0 + r) * K + k0 + (tid & 7) * 8;
            areg[j][0] = *(const f32x4*)src;
            areg[j][1] = *(const f32x4*)(src + 4);
        }
    };
    auto writeA32 = [&](int buf) {  // convert + swizzled 16B ds_write
#pragma unroll
        for (int j = 0; j < 2; ++j) {
            const int r = j * 128 + (tid >> 3);
            us8 hv;
#pragma unroll
            for (int e = 0; e < 4; ++e) {
                hv[e] = f2h(areg[j][0][e]);
                hv[e + 4] = f2h(areg[j][1][e]);
            }
            const int pos = (tid & 7) ^ (r & 7);
            *(us8*)&lds[buf + r * 64 + pos * 8] = hv;
        }
    };

    const int nt = K / 64;
    // prologue: fill buffer 0
    if constexpr (AF32) {
        loadA32(0);
        writeA32(0);
    } else {
        stageA16(0, 0);
    }
    stageB(0, 0);

    for (int t = 0; t < nt; ++t) {
        const int cur = (t & 1) * BUF;
        const int nxt = BUF - cur;
        __syncthreads();  // drains stage(t); protects buffer reuse
        const bool more = (t + 1 < nt);
        if (more) {
            if constexpr (AF32) {
                loadA32((t + 1) * 64);
                stageB(nxt, (t + 1) * 64);
            } else {
                stageA16(nxt, (t + 1) * 64);
                stageB(nxt, (t + 1) * 64);
            }
        }

#pragma unroll
        for (int kh = 0; kh < 2; ++kh) {
            half8 aa[2], bb[4];
            const int q = kh * 4 + c0;
#pragma unroll
            for (int mi = 0; mi < 2; ++mi) {
                const int r = wr * 32 + mi * 16 + (l & 15);
                const int off = cur + r * 64 + ((q ^ (l & 7)) * 8);
                aa[mi] = __builtin_bit_cast(half8, *(const short8*)&lds[off]);
            }
#pragma unroll
            for (int ni = 0; ni < 4; ++ni) {
                const int r = wc * 64 + ni * 16 + (l & 15);
                const int off = cur + 16384 + r * 64 + ((q ^ (l & 7)) * 8);
                bb[ni] = __builtin_bit_cast(half8, *(const short8*)&lds[off]);
            }
            __builtin_amdgcn_s_setprio(1);
#pragma unroll
            for (int mi = 0; mi < 2; ++mi)
#pragma unroll
                for (int ni = 0; ni < 4; ++ni)
                    acc[mi][ni] = __builtin_amdgcn_mfma_f32_16x16x32_f16(
                        aa[mi], bb[ni], acc[mi][ni], 0, 0, 0);
            __builtin_amdgcn_s_setprio(0);
        }

        if constexpr (AF32) {
            if (more) writeA32(nxt);  // write-late: after MFMA, before barrier
        }
    }

    __syncthreads();  // ALL frag reads complete before LDS reuse by the spill

    // acc(+bias) -> LDS x[t][h] f16, stride 130 (65 dwords: bank-spread)
    float bv[4];
#pragma unroll
    for (int ni = 0; ni < 4; ++ni)
        bv[ni] = bias[n0 + wc * 64 + ni * 16 + (l & 15)];
#pragma unroll
    for (int mi = 0; mi < 2; ++mi) {
        const int t0 = wr * 32 + mi * 16 + ((l >> 4) << 2);
#pragma unroll
        for (int ni = 0; ni < 4; ++ni) {
            const int h = wc * 64 + ni * 16 + (l & 15);
#pragma unroll
            for (int r = 0; r < 4; ++r)
                lds[(t0 + r) * 130 + h] = f2h(acc[mi][ni][r] + bv[ni]);
        }
    }
    __syncthreads();

    // scan: threads 0..127 each own one h column; snntorch Leaky subtract
    if (tid < 128) {
        const int h = tid;
        ushort_t* sp = Sout + (size_t)m0 * 512 + n0 + h;
        float m = 0.f;
#pragma unroll 4
        for (int t = 0; t < T_; ++t) {
            const float xv = h2f(lds[t * 130 + h]);
            const float r = (m - THR > 0.f) ? THR : 0.f;
            m = BETA * m + xv - r;
            sp[(size_t)t * 512] = (m - THR > 0.f) ? (ushort_t)0x3C00 : (ushort_t)0;
        }
    }
}

// ---------------------------------------------------------------------------
// f16 MFMA GEMM with fused MIL head — R24: ported to the proven 16-wave
// 256M x 128N / BK=64 dbuf structure (gemm_scan<0> skeleton; R21's +15-20%
// on the scan kernels motivates the same conversion here).
// p = relu(C+bias) dot u per 64-col strip -> part[strip][row].
// Grid (4,64) = 256 wgs = 1/CU; clip-grouped XCD map. Epilogue math order
// identical to the old 4-wave version -> bit-identical part values.
// ---------------------------------------------------------------------------
__global__ __launch_bounds__(1024, 1) void gemm_mil(
    const ushort_t* __restrict__ Ap, const ushort_t* __restrict__ Bp,
    const float* __restrict__ bias, const float* __restrict__ Uv,
    float* __restrict__ part, int N, int K) {
    constexpr int BUF = 24576;  // ushorts per buffer (48KB)
    __shared__ ushort_t lds[2 * BUF];  // 96KB

    const int tid = threadIdx.x;
    const int w = tid >> 6, l = tid & 63;  // 16 waves
    const int flat = blockIdx.y * gridDim.x + blockIdx.x;
    const int mrow = ((flat >> 5) << 3) | (flat & 7);  // [0,64): 256-row blk
    const int st = (flat >> 3) & 3;                    // [0,4): 128-col strip
    const int n0 = st * 128;
    const int m0 = mrow * 256;
    const int wr = w >> 1, wc = w & 1;

    f32x4 acc[2][4];
#pragma unroll
    for (int mi = 0; mi < 2; ++mi)
#pragma unroll
        for (int ni = 0; ni < 4; ++ni) acc[mi][ni] = (f32x4){0.f, 0.f, 0.f, 0.f};

    const int c0 = l >> 4;
    const int schunk = (l & 7) ^ ((l >> 3) & 7);

    auto stageB = [&](int buf, int k0) {
        const int r = w * 8 + (l >> 3);
        GLDS(Bp + (size_t)(n0 + r) * K + k0 + schunk * 8,
             &lds[buf + 16384 + w * 512]);
    };
    auto stageA = [&](int buf, int k0) {
#pragma unroll
        for (int j = 0; j < 2; ++j) {
            const int seg = w * 2 + j;  // 0..31
            const int r = seg * 8 + (l >> 3);
            GLDS(Ap + (size_t)(m0 + r) * K + k0 + schunk * 8,
                 &lds[buf + seg * 512]);
        }
    };

    const int nt = K / 64;
    stageA(0, 0);
    stageB(0, 0);

    for (int t = 0; t < nt; ++t) {
        const int cur = (t & 1) * BUF;
        const int nxt = BUF - cur;
        __syncthreads();
        if (t + 1 < nt) {
            stageA(nxt, (t + 1) * 64);
            stageB(nxt, (t + 1) * 64);
        }

#pragma unroll
        for (int kh = 0; kh < 2; ++kh) {
            half8 aa[2], bb[4];
            const int q = kh * 4 + c0;
#pragma unroll
            for (int mi = 0; mi < 2; ++mi) {
                const int r = wr * 32 + mi * 16 + (l & 15);
                const int off = cur + r * 64 + ((q ^ (l & 7)) * 8);
                aa[mi] = __builtin_bit_cast(half8, *(const short8*)&lds[off]);
            }
#pragma unroll
            for (int ni = 0; ni < 4; ++ni) {
                const int r = wc * 64 + ni * 16 + (l & 15);
                const int off = cur + 16384 + r * 64 + ((q ^ (l & 7)) * 8);
                bb[ni] = __builtin_bit_cast(half8, *(const short8*)&lds[off]);
            }
            __builtin_amdgcn_s_setprio(1);
#pragma unroll
            for (int mi = 0; mi < 2; ++mi)
#pragma unroll
                for (int ni = 0; ni < 4; ++ni)
                    acc[mi][ni] = __builtin_amdgcn_mfma_f32_16x16x32_f16(
                        aa[mi], bb[ni], acc[mi][ni], 0, 0, 0);
            __builtin_amdgcn_s_setprio(0);
        }
    }

    // fused MIL: per row partial = sum_col relu(acc+bias)*u[col]
    float bv[4], uc[4];
#pragma unroll
    for (int ni = 0; ni < 4; ++ni) {
        const int col = n0 + wc * 64 + ni * 16 + (l & 15);
        bv[ni] = bias[col];
        uc[ni] = Uv[col];
    }
    const int strip = (n0 >> 6) + wc;  // 0..7
#pragma unroll
    for (int mi = 0; mi < 2; ++mi) {
        float p[4];
#pragma unroll
        for (int r = 0; r < 4; ++r) {
            float s = 0.f;
#pragma unroll
            for (int ni = 0; ni < 4; ++ni)
                s += fmaxf(acc[mi][ni][r] + bv[ni], 0.f) * uc[ni];
            p[r] = s;
        }
#pragma unroll
        for (int off = 1; off <= 8; off <<= 1)
#pragma unroll
            for (int r = 0; r < 4; ++r) p[r] += __shfl_xor(p[r], off);
        if ((l & 15) == 0) {
            const int row0 = m0 + wr * 32 + mi * 16 + ((l >> 4) << 2);
#pragma unroll
            for (int r = 0; r < 4; ++r)
                part[(size_t)strip * M_ + row0 + r] = p[r];
        }
    }
}

// ---------------------------------------------------------------------------
// Split-bf16 3-product GEMM for Wc = W1 @ Wf, BK=64 + dbuf.
// Tile 128x128, 4 waves (2x2). Grid (8,4)=32 wgs. LDS 128KB = 2 x 32768
// ushorts (Ah/Al/Bh/Bl 16 segs each per buffer). Emits single f16 plane.
// ---------------------------------------------------------------------------
__global__ __launch_bounds__(256, 1) void gemm_bf16_wc(
    const ushort_t* __restrict__ Ah, const ushort_t* __restrict__ Al,
    const ushort_t* __restrict__ Bh, const ushort_t* __restrict__ Bl,
    ushort_t* __restrict__ Cout, int N, int K) {
    constexpr int BUF = 32768;  // ushorts per buffer (64KB)
    __shared__ ushort_t lds[2 * BUF];

    const int tid = threadIdx.x;
    const int w = tid >> 6, l = tid & 63;
    const int flat = blockIdx.y * gridDim.x + blockIdx.x;
    const int n0 = (flat % gridDim.x) * 128;
    const int m0 = (flat / gridDim.x) * 128;
    const int wr = w >> 1, wc = w & 1;

    f32x4 acc[4][4];
#pragma unroll
    for (int mi = 0; mi < 4; ++mi)
#pragma unroll
        for (int ni = 0; ni < 4; ++ni) acc[mi][ni] = (f32x4){0.f, 0.f, 0.f, 0.f};

    const int c0 = l >> 4;
    const int schunk = (l & 7) ^ ((l >> 3) & 7);

    auto stage = [&](int buf, int k0) {
        // 64 segs of 1KB: Ah 0-15, Al 16-31, Bh 32-47, Bl 48-63; 16/wave
#pragma unroll
        for (int j = 0; j < 16; ++j) {
            const int g = w * 16 + j;
            const int p = g >> 4, seg = g & 15;
            const int r = seg * 8 + (l >> 3);
            const ushort_t* pl = (p == 0) ? Ah : (p == 1) ? Al : (p == 2) ? Bh : Bl;
            const int rb = (p < 2) ? m0 : n0;
            GLDS(pl + (size_t)(rb + r) * K + k0 + schunk * 8,
                 &lds[buf + g * 512]);
        }
    };

    const int nt = K / 64;
    stage(0, 0);
    for (int t = 0; t < nt; ++t) {
        const int cur = (t & 1) * BUF;
        const int nxt = BUF - cur;
        __syncthreads();
        if (t + 1 < nt) stage(nxt, (t + 1) * 64);

#pragma unroll
        for (int kh = 0; kh < 2; ++kh) {
            short8 ah[4], al[4], bh[4], bl[4];
            const int q = kh * 4 + c0;
#pragma unroll
            for (int mi = 0; mi < 4; ++mi) {
                const int r = wr * 64 + mi * 16 + (l & 15);
                const int off = r * 64 + ((q ^ (l & 7)) * 8);
                ah[mi] = *(const short8*)&lds[cur + off];
                al[mi] = *(const short8*)&lds[cur + 8192 + off];
            }
#pragma unroll
            for (int ni = 0; ni < 4; ++ni) {
                const int r = wc * 64 + ni * 16 + (l & 15);
                const int off = r * 64 + ((q ^ (l & 7)) * 8);
                bh[ni] = *(const short8*)&lds[cur + 16384 + off];
                bl[ni] = *(const short8*)&lds[cur + 24576 + off];
            }
            __builtin_amdgcn_s_setprio(1);
#pragma unroll
            for (int mi = 0; mi < 4; ++mi)
#pragma unroll
                for (int ni = 0; ni < 4; ++ni) {
                    acc[mi][ni] = __builtin_amdgcn_mfma_f32_16x16x32_bf16(
                        ah[mi], bh[ni], acc[mi][ni], 0, 0, 0);
                    acc[mi][ni] = __builtin_amdgcn_mfma_f32_16x16x32_bf16(
                        ah[mi], bl[ni], acc[mi][ni], 0, 0, 0);
                    acc[mi][ni] = __builtin_amdgcn_mfma_f32_16x16x32_bf16(
                        al[mi], bh[ni], acc[mi][ni], 0, 0, 0);
                }
            __builtin_amdgcn_s_setprio(0);
        }
    }

#pragma unroll
    for (int ni = 0; ni < 4; ++ni) {
        const int col = n0 + wc * 64 + ni * 16 + (l & 15);
#pragma unroll
        for (int mi = 0; mi < 4; ++mi) {
            const int row0 = m0 + wr * 64 + mi * 16 + ((l >> 4) << 2);
#pragma unroll
            for (int r = 0; r < 4; ++r)
                Cout[(size_t)(row0 + r) * N + col] = f2h(acc[mi][ni][r]);
        }
    }
}

// ---------------------------------------------------------------------------
// Sectioned prep (one launch, 1410 blocks):
//   [0,256):      W1 -> bf16 hi/lo planes
//   [256,512):    W2 -> f16
//   [512,768):    Mw1 -> f16
//   [768,896):    bc[j] = b1[j] + W1[j,:]@bf  (wave per j)
//   [896,898):    u[j] = Mw3@Mw2[:,j]; uc[512] = Mw3@Mb2+Mb3
//   [898,1410):   Wf -> WfT bf16 hi/lo planes (32x32 transpose tiles)
// ---------------------------------------------------------------------------
__global__ __launch_bounds__(256) void prep_small(
    const float* __restrict__ W1, const float* __restrict__ W2,
    const float* __restrict__ Mw1, const float* __restrict__ bfv,
    const float* __restrict__ b1, const float* __restrict__ Mw2,
    const float* __restrict__ Mb2, const float* __restrict__ Mw3,
    const float* __restrict__ Mb3, const float* __restrict__ Wf,
    ushort_t* __restrict__ w1h, ushort_t* __restrict__ w1l,
    ushort_t* __restrict__ w2f, ushort_t* __restrict__ m1f,
    float* __restrict__ bc, float* __restrict__ uc,
    ushort_t* __restrict__ wfTh, ushort_t* __restrict__ wfTl) {
    __shared__ float tile[32][33];
    const int blk = blockIdx.x;
    const int tid = threadIdx.x;
    if (blk < 256) {
        const int i = blk * 256 + tid;
        f32x4 v = ((const f32x4*)W1)[i];
        us4 h, ll;
#pragma unroll
        for (int e = 0; e < 4; ++e) {
            const unsigned short hb = f2bf(v[e]);
            h[e] = hb;
            ll[e] = f2bf(v[e] - bf2f(hb));
        }
        ((us4*)w1h)[i] = h;
        ((us4*)w1l)[i] = ll;
    } else if (blk < 512) {
        const int i = (blk - 256) * 256 + tid;
        f32x4 v = ((const f32x4*)W2)[i];
        us4 h;
#pragma unroll
        for (int e = 0; e < 4; ++e) h[e] = f2h(v[e]);
        ((us4*)w2f)[i] = h;
    } else if (blk < 768) {
        const int i = (blk - 512) * 256 + tid;
        f32x4 v = ((const f32x4*)Mw1)[i];
        us4 h;
#pragma unroll
        for (int e = 0; e < 4; ++e) h[e] = f2h(v[e]);
        ((us4*)m1f)[i] = h;
    } else if (blk < 896) {
        const int w = tid >> 6, l = tid & 63;
        const int j = (blk - 768) * 4 + w;
        const float* row = W1 + (size_t)j * 512;
        float a = 0.f;
#pragma unroll
        for (int i = 0; i < 8; ++i) a += row[l + i * 64] * bfv[l + i * 64];
#pragma unroll
        for (int off = 32; off >= 1; off >>= 1) a += __shfl_xor(a, off);
        if (l == 0) bc[j] = a + b1[j];
    } else if (blk < 898) {
        const int j = (blk - 896) * 256 + tid;  // 0..511
        float a = 0.f;
        for (int i = 0; i < 32; ++i) a += Mw3[i] * Mw2[(size_t)i * 512 + j];
        uc[j] = a;
        if (j == 0) {
            float c = Mb3[0];
            for (int i = 0; i < 32; ++i) c += Mw3[i] * Mb2[i];
            uc[512] = c;
        }
    } else {
        const int idx = blk - 898;          // 0..511
        const int k0 = (idx & 31) * 32;     // Wf col tile
        const int i0 = (idx >> 5) * 32;     // Wf row tile
        const int tx = tid & 31;
        const int ty = tid >> 5;  // 0..7
#pragma unroll
        for (int e = 0; e < 4; ++e) {
            const int i = ty + e * 8;
            tile[i][tx] = Wf[(size_t)(i0 + i) * 1024 + k0 + tx];
        }
        __syncthreads();
#pragma unroll
        for (int e = 0; e < 4; ++e) {
            const int kk = ty + e * 8;
            const float v = tile[tx][kk];
            const unsigned short h = f2bf(v);
            wfTh[(size_t)(k0 + kk) * 512 + i0 + tx] = h;
            wfTl[(size_t)(k0 + kk) * 512 + i0 + tx] = f2bf(v - bf2f(h));
        }
    }
}

// ---------------------------------------------------------------------------
// Tail: pre[row] = sum_{s<8} part[s][row] + c; top-17 on pre (sigmoid
// monotonic), mean of sigmoid(selected). One wave per clip.
// ---------------------------------------------------------------------------
__global__ __launch_bounds__(64) void tail_topk(const float* __restrict__ part,
                                                const float* __restrict__ uc,
                                                float* __restrict__ out) {
    const int b = blockIdx.x;
    const int lane = threadIdx.x;
    const float c = uc[512];
    float v[4];
#pragma unroll
    for (int i = 0; i < 4; ++i) {
        const int row = b * T_ + lane + i * 64;
        float a = 0.f;
#pragma unroll
        for (int s = 0; s < 8; ++s) a += part[(size_t)s * M_ + row];
        v[i] = a + c;
    }
    float sum = 0.f;
    for (int iter = 0; iter < 17; ++iter) {
        float mv = v[0];
        int mslot = 0;
#pragma unroll
        for (int i = 1; i < 4; ++i)
            if (v[i] > mv) { mv = v[i]; mslot = i; }
        float bv = mv;
        int bl = lane, bs = mslot;
#pragma unroll
        for (int off = 32; off >= 1; off >>= 1) {
            const float ov = __shfl_xor(bv, off);
            const int ol = __shfl_xor(bl, off);
            const int os = __shfl_xor(bs, off);
            if (ov > bv || (ov == bv && ol < bl)) { bv = ov; bl = ol; bs = os; }
        }
        sum += 1.f / (1.f + expf(-bv));
        if (lane == bl) v[bs] = -1e30f;
    }
    if (lane == 0) out[b] = sum * (1.f / 17.f);
}

// ---------------------------------------------------------------------------
// Orchestration (6 launches):
//   prep_small (weights + Wf transpose)
//   wcf   <- gemm_bf16_wc(W1 planes @ WfT^T)      [BK=64 dbuf]
//   sbuf1 <- gemm_scan<1>(f_f(f32) @ wcf^T + bc)  [16-wave, 128N tile]
//   sbuf2 <- gemm_scan<0>(sbuf1 @ w2f^T + b2)     [16-wave, 128N tile]
//   part  <- gemm_mil(sbuf2 @ m1f^T + Mb1)        [16-wave, 128N, MIL fused]
//   out   <- tail_topk(part)
// ---------------------------------------------------------------------------
extern "C" void kernel_launch(void* const* d_in, const int* in_sizes, int n_in,
                              void* d_out, int out_size, void* d_ws, size_t ws_size,
                              hipStream_t stream) {
    const float* f_f = (const float*)d_in[0];
    const float* Wf  = (const float*)d_in[2];
    const float* bf  = (const float*)d_in[3];
    const float* W1  = (const float*)d_in[4];
    const float* b1  = (const float*)d_in[5];
    const float* W2  = (const float*)d_in[6];
    const float* b2  = (const float*)d_in[7];
    const float* Mw1 = (const float*)d_in[8];
    const float* Mb1 = (const float*)d_in[9];
    const float* Mw2 = (const float*)d_in[10];
    const float* Mb2 = (const float*)d_in[11];
    const float* Mw3 = (const float*)d_in[12];
    const float* Mb3 = (const float*)d_in[13];
    float* out = (float*)d_out;

    char* ws = (char*)d_ws;
    const size_t NE = (size_t)M_ * H_;   // 8.39M elems
    ushort_t* sbuf1 = (ushort_t*)ws;                     // f16 spikes 1
    ushort_t* sbuf2 = sbuf1 + NE;                        // f16 spikes 2
    ushort_t* w1h = sbuf2 + NE;                          // bf16 (wc input)
    ushort_t* w1l = w1h + 262144;
    ushort_t* w2f = w1l + 262144;                        // f16 single
    ushort_t* m1f = w2f + 262144;                        // f16 single
    ushort_t* wfTh = m1f + 262144;                       // bf16 [1024,512]
    ushort_t* wfTl = wfTh + 524288;
    ushort_t* wcf = wfTl + 524288;                       // f16 [512,1024]
    float* bc = (float*)(wcf + 524288);
    float* uc = bc + 512;                                // u[512] + c
    float* part = uc + 513 + 63;                         // [8][16384] f32

    const dim3 blk(256);

    prep_small<<<dim3(1410), blk, 0, stream>>>(W1, W2, Mw1, bf, b1, Mw2, Mb2,
                                               Mw3, Mb3, Wf, w1h, w1l, w2f,
                                               m1f, bc, uc, wfTh, wfTl);

    // Wc = W1 @ Wf -> f16 [512,1024]
    gemm_bf16_wc<<<dim3(8, 4), blk, 0, stream>>>(w1h, w1l, wfTh, wfTl, wcf,
                                                 1024, 512);
    // x1 = f_f @ Wc^T + bc, fused scan1 -> sbuf1 (f32 A, in-kernel convert)
    gemm_scan<1><<<dim3(4, 64), dim3(1024), 0, stream>>>(f_f, wcf, bc, sbuf1,
                                                         1024);
    // x2 = sbuf1 @ W2^T + b2, fused scan2 -> sbuf2
    gemm_scan<0><<<dim3(4, 64), dim3(1024), 0, stream>>>(sbuf1, w2f, b2, sbuf2,
                                                         512);
    // z-GEMM with fused MIL head -> part[8][M]
    gemm_mil<<<dim3(4, 64), dim3(1024), 0, stream>>>(sbuf2, m1f, Mb1, uc, part,
                                                     512, 512);
    tail_topk<<<dim3(B_), dim3(64), 0, stream>>>(part, uc, out);
}

// Round 25
// 102.942 us; speedup vs baseline: 1.0117x; 1.0016x over previous
//
#include <hip/hip_runtime.h>
#include <math.h>

#define BETA 0.9f
#define THR 1.0f

constexpr int B_ = 64, T_ = 256, F_ = 1024, H_ = 512;
constexpr int M_ = B_ * T_;  // 16384 rows

typedef float f32x4 __attribute__((ext_vector_type(4)));
typedef short short8 __attribute__((ext_vector_type(8)));
typedef _Float16 half8 __attribute__((ext_vector_type(8)));
typedef unsigned short us4 __attribute__((ext_vector_type(4)));
typedef unsigned short us8 __attribute__((ext_vector_type(8)));
typedef unsigned short ushort_t;

// ---- bf16 helpers (RNE) ----------------------------------------------------
static __device__ __forceinline__ unsigned short f2bf(float x) {
    unsigned b = __builtin_bit_cast(unsigned, x);
    unsigned r = (b + 0x7FFFu + ((b >> 16) & 1u)) >> 16;
    return (unsigned short)r;
}
static __device__ __forceinline__ float bf2f(unsigned short u) {
    unsigned v = ((unsigned)u) << 16;
    return __builtin_bit_cast(float, v);
}
// ---- f16 helpers ------------------------------------------------------------
static __device__ __forceinline__ unsigned short f2h(float x) {
    _Float16 h = (_Float16)x;
    return __builtin_bit_cast(unsigned short, h);
}
static __device__ __forceinline__ float h2f(unsigned short u) {
    return (float)__builtin_bit_cast(_Float16, u);
}
// BK=32 swizzle (64B rows, 4 chunks) — used by prep only.
static __device__ __forceinline__ int swz(int r) {
    return ((r >> 2) & 3) ^ (r & 3);
}

#define GLDS(srcp, dstp)                                                      \
    __builtin_amdgcn_global_load_lds(                                         \
        (const __attribute__((address_space(1))) unsigned int*)(srcp),        \
        (__attribute__((address_space(3))) unsigned int*)(dstp), 16, 0, 0)

// ---------------------------------------------------------------------------
// Fused f16 GEMM + leaky scan — FINAL (best of 25 rounds, 103.1us).
// 128-wide N-tile, 16 waves (1024 threads), BK=64, 2-phase dbuf.
// AF32=0: A f16 staged via GLDS (pre-swizzled). AF32=1: A f32 (f_f direct),
// reg-load + convert f2h + swizzled ds_write after MFMA (write-late).
// Wave w: rows (w>>1)*32..+31, cols (w&1)*64..+63 (2 m-frags x 4 n-frags).
// Grid (4 strips, 64 clips) = 256 wgs = 1/CU; clip-grouped XCD map
// clip=((flat>>5)<<3)|(flat&7) (bijective), strip=(flat>>3)&3.
// LDS: BUF=24576 ushorts/buffer (A 32 segs @ [0,16384), B 16 segs @
// [16384,24576)). Involution pos = c ^ (r&7) (128B rows, 8x16B chunks).
// Scan buffer 256x130 ushorts (65-dword stride, bank-spread) at [0,33280);
// safe: pre-spill __syncthreads() completes all frag reads first.
// ---------------------------------------------------------------------------
template <int AF32>
__global__ __launch_bounds__(1024, 1) void gemm_scan(
    const void* __restrict__ Asrc, const ushort_t* __restrict__ Bp,
    const float* __restrict__ bias, ushort_t* __restrict__ Sout, int K) {
    constexpr int BUF = 24576;  // ushorts per buffer (48KB)
    __shared__ ushort_t lds[2 * BUF];  // 96KB

    const int tid = threadIdx.x;
    const int w = tid >> 6, l = tid & 63;  // 16 waves
    const int flat = blockIdx.y * gridDim.x + blockIdx.x;
    const int clip = ((flat >> 5) << 3) | (flat & 7);  // [0,64)
    const int strip = (flat >> 3) & 3;                 // [0,4)
    const int n0 = strip * 128;
    const int m0 = clip * 256;
    const int wr = w >> 1, wc = w & 1;

    f32x4 acc[2][4];
#pragma unroll
    for (int mi = 0; mi < 2; ++mi)
#pragma unroll
        for (int ni = 0; ni < 4; ++ni) acc[mi][ni] = (f32x4){0.f, 0.f, 0.f, 0.f};

    const int c0 = l >> 4;
    const int schunk = (l & 7) ^ ((l >> 3) & 7);  // pre-swizzled source chunk

    // AF32 staging state: 2 row-chunks of 8 f32 (2 f32x4 each) per thread.
    f32x4 areg[2][2];

    auto stageB = [&](int buf, int k0) {
        // B tile 128x64 f16 = 16KB = 16 segs; 1 per wave
        const int r = w * 8 + (l >> 3);
        GLDS(Bp + (size_t)(n0 + r) * K + k0 + schunk * 8,
             &lds[buf + 16384 + w * 512]);
    };
    auto stageA16 = [&](int buf, int k0) {
        // A tile 256x64 f16 = 32KB = 32 segs; 2 per wave
#pragma unroll
        for (int j = 0; j < 2; ++j) {
            const int seg = w * 2 + j;  // 0..31
            const int r = seg * 8 + (l >> 3);
            GLDS((const ushort_t*)Asrc + (size_t)(m0 + r) * K + k0 + schunk * 8,
                 &lds[buf + seg * 512]);
        }
    };
    auto loadA32 = [&](int k0) {  // 256x64 f32: 16 f32/thread, 8 lanes/row
#pragma unroll
        for (int j = 0; j < 2; ++j) {
            const int r = j * 128 + (tid >> 3);
            const float* src =
                (const float*)Asrc + (size_t)(m0 + r) * K + k0 + (tid & 7) * 8;
            areg[j][0] = *(const f32x4*)src;
            areg[j][1] = *(const f32x4*)(src + 4);
        }
    };
    auto writeA32 = [&](int buf) {  // convert + swizzled 16B ds_write
#pragma unroll
        for (int j = 0; j < 2; ++j) {
            const int r = j * 128 + (tid >> 3);
            us8 hv;
#pragma unroll
            for (int e = 0; e < 4; ++e) {
                hv[e] = f2h(areg[j][0][e]);
                hv[e + 4] = f2h(areg[j][1][e]);
            }
            const int pos = (tid & 7) ^ (r & 7);
            *(us8*)&lds[buf + r * 64 + pos * 8] = hv;
        }
    };

    const int nt = K / 64;
    // prologue: fill buffer 0
    if constexpr (AF32) {
        loadA32(0);
        writeA32(0);
    } else {
        stageA16(0, 0);
    }
    stageB(0, 0);

    for (int t = 0; t < nt; ++t) {
        const int cur = (t & 1) * BUF;
        const int nxt = BUF - cur;
        __syncthreads();  // drains stage(t); protects buffer reuse
        const bool more = (t + 1 < nt);
        if (more) {
            if constexpr (AF32) {
                loadA32((t + 1) * 64);
                stageB(nxt, (t + 1) * 64);
            } else {
                stageA16(nxt, (t + 1) * 64);
                stageB(nxt, (t + 1) * 64);
            }
        }

#pragma unroll
        for (int kh = 0; kh < 2; ++kh) {
            half8 aa[2], bb[4];
            const int q = kh * 4 + c0;
#pragma unroll
            for (int mi = 0; mi < 2; ++mi) {
                const int r = wr * 32 + mi * 16 + (l & 15);
                const int off = cur + r * 64 + ((q ^ (l & 7)) * 8);
                aa[mi] = __builtin_bit_cast(half8, *(const short8*)&lds[off]);
            }
#pragma unroll
            for (int ni = 0; ni < 4; ++ni) {
                const int r = wc * 64 + ni * 16 + (l & 15);
                const int off = cur + 16384 + r * 64 + ((q ^ (l & 7)) * 8);
                bb[ni] = __builtin_bit_cast(half8, *(const short8*)&lds[off]);
            }
            __builtin_amdgcn_s_setprio(1);
#pragma unroll
            for (int mi = 0; mi < 2; ++mi)
#pragma unroll
                for (int ni = 0; ni < 4; ++ni)
                    acc[mi][ni] = __builtin_amdgcn_mfma_f32_16x16x32_f16(
                        aa[mi], bb[ni], acc[mi][ni], 0, 0, 0);
            __builtin_amdgcn_s_setprio(0);
        }

        if constexpr (AF32) {
            if (more) writeA32(nxt);  // write-late: after MFMA, before barrier
        }
    }

    __syncthreads();  // ALL frag reads complete before LDS reuse by the spill

    // acc(+bias) -> LDS x[t][h] f16, stride 130 (65 dwords: bank-spread)
    float bv[4];
#pragma unroll
    for (int ni = 0; ni < 4; ++ni)
        bv[ni] = bias[n0 + wc * 64 + ni * 16 + (l & 15)];
#pragma unroll
    for (int mi = 0; mi < 2; ++mi) {
        const int t0 = wr * 32 + mi * 16 + ((l >> 4) << 2);
#pragma unroll
        for (int ni = 0; ni < 4; ++ni) {
            const int h = wc * 64 + ni * 16 + (l & 15);
#pragma unroll
            for (int r = 0; r < 4; ++r)
                lds[(t0 + r) * 130 + h] = f2h(acc[mi][ni][r] + bv[ni]);
        }
    }
    __syncthreads();

    // scan: threads 0..127 each own one h column; snntorch Leaky subtract
    if (tid < 128) {
        const int h = tid;
        ushort_t* sp = Sout + (size_t)m0 * 512 + n0 + h;
        float m = 0.f;
#pragma unroll 4
        for (int t = 0; t < T_; ++t) {
            const float xv = h2f(lds[t * 130 + h]);
            const float r = (m - THR > 0.f) ? THR : 0.f;
            m = BETA * m + xv - r;
            sp[(size_t)t * 512] = (m - THR > 0.f) ? (ushort_t)0x3C00 : (ushort_t)0;
        }
    }
}

// ---------------------------------------------------------------------------
// f16 MFMA GEMM with fused MIL head — 16-wave 256M x 128N / BK=64 dbuf
// (gemm_scan<0> skeleton). p = relu(C+bias) dot u per 64-col strip ->
// part[strip][row]. Grid (4,64) = 256 wgs = 1/CU; clip-grouped XCD map.
// ---------------------------------------------------------------------------
__global__ __launch_bounds__(1024, 1) void gemm_mil(
    const ushort_t* __restrict__ Ap, const ushort_t* __restrict__ Bp,
    const float* __restrict__ bias, const float* __restrict__ Uv,
    float* __restrict__ part, int N, int K) {
    constexpr int BUF = 24576;  // ushorts per buffer (48KB)
    __shared__ ushort_t lds[2 * BUF];  // 96KB

    const int tid = threadIdx.x;
    const int w = tid >> 6, l = tid & 63;  // 16 waves
    const int flat = blockIdx.y * gridDim.x + blockIdx.x;
    const int mrow = ((flat >> 5) << 3) | (flat & 7);  // [0,64): 256-row blk
    const int st = (flat >> 3) & 3;                    // [0,4): 128-col strip
    const int n0 = st * 128;
    const int m0 = mrow * 256;
    const int wr = w >> 1, wc = w & 1;

    f32x4 acc[2][4];
#pragma unroll
    for (int mi = 0; mi < 2; ++mi)
#pragma unroll
        for (int ni = 0; ni < 4; ++ni) acc[mi][ni] = (f32x4){0.f, 0.f, 0.f, 0.f};

    const int c0 = l >> 4;
    const int schunk = (l & 7) ^ ((l >> 3) & 7);

    auto stageB = [&](int buf, int k0) {
        const int r = w * 8 + (l >> 3);
        GLDS(Bp + (size_t)(n0 + r) * K + k0 + schunk * 8,
             &lds[buf + 16384 + w * 512]);
    };
    auto stageA = [&](int buf, int k0) {
#pragma unroll
        for (int j = 0; j < 2; ++j) {
            const int seg = w * 2 + j;  // 0..31
            const int r = seg * 8 + (l >> 3);
            GLDS(Ap + (size_t)(m0 + r) * K + k0 + schunk * 8,
                 &lds[buf + seg * 512]);
        }
    };

    const int nt = K / 64;
    stageA(0, 0);
    stageB(0, 0);

    for (int t = 0; t < nt; ++t) {
        const int cur = (t & 1) * BUF;
        const int nxt = BUF - cur;
        __syncthreads();
        if (t + 1 < nt) {
            stageA(nxt, (t + 1) * 64);
            stageB(nxt, (t + 1) * 64);
        }

#pragma unroll
        for (int kh = 0; kh < 2; ++kh) {
            half8 aa[2], bb[4];
            const int q = kh * 4 + c0;
#pragma unroll
            for (int mi = 0; mi < 2; ++mi) {
                const int r = wr * 32 + mi * 16 + (l & 15);
                const int off = cur + r * 64 + ((q ^ (l & 7)) * 8);
                aa[mi] = __builtin_bit_cast(half8, *(const short8*)&lds[off]);
            }
#pragma unroll
            for (int ni = 0; ni < 4; ++ni) {
                const int r = wc * 64 + ni * 16 + (l & 15);
                const int off = cur + 16384 + r * 64 + ((q ^ (l & 7)) * 8);
                bb[ni] = __builtin_bit_cast(half8, *(const short8*)&lds[off]);
            }
            __builtin_amdgcn_s_setprio(1);
#pragma unroll
            for (int mi = 0; mi < 2; ++mi)
#pragma unroll
                for (int ni = 0; ni < 4; ++ni)
                    acc[mi][ni] = __builtin_amdgcn_mfma_f32_16x16x32_f16(
                        aa[mi], bb[ni], acc[mi][ni], 0, 0, 0);
            __builtin_amdgcn_s_setprio(0);
        }
    }

    // fused MIL: per row partial = sum_col relu(acc+bias)*u[col]
    float bv[4], uc[4];
#pragma unroll
    for (int ni = 0; ni < 4; ++ni) {
        const int col = n0 + wc * 64 + ni * 16 + (l & 15);
        bv[ni] = bias[col];
        uc[ni] = Uv[col];
    }
    const int strip = (n0 >> 6) + wc;  // 0..7
#pragma unroll
    for (int mi = 0; mi < 2; ++mi) {
        float p[4];
#pragma unroll
        for (int r = 0; r < 4; ++r) {
            float s = 0.f;
#pragma unroll
            for (int ni = 0; ni < 4; ++ni)
                s += fmaxf(acc[mi][ni][r] + bv[ni], 0.f) * uc[ni];
            p[r] = s;
        }
#pragma unroll
        for (int off = 1; off <= 8; off <<= 1)
#pragma unroll
            for (int r = 0; r < 4; ++r) p[r] += __shfl_xor(p[r], off);
        if ((l & 15) == 0) {
            const int row0 = m0 + wr * 32 + mi * 16 + ((l >> 4) << 2);
#pragma unroll
            for (int r = 0; r < 4; ++r)
                part[(size_t)strip * M_ + row0 + r] = p[r];
        }
    }
}

// ---------------------------------------------------------------------------
// Split-bf16 3-product GEMM for Wc = W1 @ Wf, BK=64 + dbuf.
// Tile 128x128, 4 waves (2x2). Grid (8,4)=32 wgs. LDS 128KB = 2 x 32768
// ushorts (Ah/Al/Bh/Bl 16 segs each per buffer). Emits single f16 plane.
// ---------------------------------------------------------------------------
__global__ __launch_bounds__(256, 1) void gemm_bf16_wc(
    const ushort_t* __restrict__ Ah, const ushort_t* __restrict__ Al,
    const ushort_t* __restrict__ Bh, const ushort_t* __restrict__ Bl,
    ushort_t* __restrict__ Cout, int N, int K) {
    constexpr int BUF = 32768;  // ushorts per buffer (64KB)
    __shared__ ushort_t lds[2 * BUF];

    const int tid = threadIdx.x;
    const int w = tid >> 6, l = tid & 63;
    const int flat = blockIdx.y * gridDim.x + blockIdx.x;
    const int n0 = (flat % gridDim.x) * 128;
    const int m0 = (flat / gridDim.x) * 128;
    const int wr = w >> 1, wc = w & 1;

    f32x4 acc[4][4];
#pragma unroll
    for (int mi = 0; mi < 4; ++mi)
#pragma unroll
        for (int ni = 0; ni < 4; ++ni) acc[mi][ni] = (f32x4){0.f, 0.f, 0.f, 0.f};

    const int c0 = l >> 4;
    const int schunk = (l & 7) ^ ((l >> 3) & 7);

    auto stage = [&](int buf, int k0) {
        // 64 segs of 1KB: Ah 0-15, Al 16-31, Bh 32-47, Bl 48-63; 16/wave
#pragma unroll
        for (int j = 0; j < 16; ++j) {
            const int g = w * 16 + j;
            const int p = g >> 4, seg = g & 15;
            const int r = seg * 8 + (l >> 3);
            const ushort_t* pl = (p == 0) ? Ah : (p == 1) ? Al : (p == 2) ? Bh : Bl;
            const int rb = (p < 2) ? m0 : n0;
            GLDS(pl + (size_t)(rb + r) * K + k0 + schunk * 8,
                 &lds[buf + g * 512]);
        }
    };

    const int nt = K / 64;
    stage(0, 0);
    for (int t = 0; t < nt; ++t) {
        const int cur = (t & 1) * BUF;
        const int nxt = BUF - cur;
        __syncthreads();
        if (t + 1 < nt) stage(nxt, (t + 1) * 64);

#pragma unroll
        for (int kh = 0; kh < 2; ++kh) {
            short8 ah[4], al[4], bh[4], bl[4];
            const int q = kh * 4 + c0;
#pragma unroll
            for (int mi = 0; mi < 4; ++mi) {
                const int r = wr * 64 + mi * 16 + (l & 15);
                const int off = r * 64 + ((q ^ (l & 7)) * 8);
                ah[mi] = *(const short8*)&lds[cur + off];
                al[mi] = *(const short8*)&lds[cur + 8192 + off];
            }
#pragma unroll
            for (int ni = 0; ni < 4; ++ni) {
                const int r = wc * 64 + ni * 16 + (l & 15);
                const int off = r * 64 + ((q ^ (l & 7)) * 8);
                bh[ni] = *(const short8*)&lds[cur + 16384 + off];
                bl[ni] = *(const short8*)&lds[cur + 24576 + off];
            }
            __builtin_amdgcn_s_setprio(1);
#pragma unroll
            for (int mi = 0; mi < 4; ++mi)
#pragma unroll
                for (int ni = 0; ni < 4; ++ni) {
                    acc[mi][ni] = __builtin_amdgcn_mfma_f32_16x16x32_bf16(
                        ah[mi], bh[ni], acc[mi][ni], 0, 0, 0);
                    acc[mi][ni] = __builtin_amdgcn_mfma_f32_16x16x32_bf16(
                        ah[mi], bl[ni], acc[mi][ni], 0, 0, 0);
                    acc[mi][ni] = __builtin_amdgcn_mfma_f32_16x16x32_bf16(
                        al[mi], bh[ni], acc[mi][ni], 0, 0, 0);
                }
            __builtin_amdgcn_s_setprio(0);
        }
    }

#pragma unroll
    for (int ni = 0; ni < 4; ++ni) {
        const int col = n0 + wc * 64 + ni * 16 + (l & 15);
#pragma unroll
        for (int mi = 0; mi < 4; ++mi) {
            const int row0 = m0 + wr * 64 + mi * 16 + ((l >> 4) << 2);
#pragma unroll
            for (int r = 0; r < 4; ++r)
                Cout[(size_t)(row0 + r) * N + col] = f2h(acc[mi][ni][r]);
        }
    }
}

// ---------------------------------------------------------------------------
// Sectioned prep (one launch, 1410 blocks):
//   [0,256):      W1 -> bf16 hi/lo planes
//   [256,512):    W2 -> f16
//   [512,768):    Mw1 -> f16
//   [768,896):    bc[j] = b1[j] + W1[j,:]@bf  (wave per j)
//   [896,898):    u[j] = Mw3@Mw2[:,j]; uc[512] = Mw3@Mb2+Mb3
//   [898,1410):   Wf -> WfT bf16 hi/lo planes (32x32 transpose tiles)
// ---------------------------------------------------------------------------
__global__ __launch_bounds__(256) void prep_small(
    const float* __restrict__ W1, const float* __restrict__ W2,
    const float* __restrict__ Mw1, const float* __restrict__ bfv,
    const float* __restrict__ b1, const float* __restrict__ Mw2,
    const float* __restrict__ Mb2, const float* __restrict__ Mw3,
    const float* __restrict__ Mb3, const float* __restrict__ Wf,
    ushort_t* __restrict__ w1h, ushort_t* __restrict__ w1l,
    ushort_t* __restrict__ w2f, ushort_t* __restrict__ m1f,
    float* __restrict__ bc, float* __restrict__ uc,
    ushort_t* __restrict__ wfTh, ushort_t* __restrict__ wfTl) {
    __shared__ float tile[32][33];
    const int blk = blockIdx.x;
    const int tid = threadIdx.x;
    if (blk < 256) {
        const int i = blk * 256 + tid;
        f32x4 v = ((const f32x4*)W1)[i];
        us4 h, ll;
#pragma unroll
        for (int e = 0; e < 4; ++e) {
            const unsigned short hb = f2bf(v[e]);
            h[e] = hb;
            ll[e] = f2bf(v[e] - bf2f(hb));
        }
        ((us4*)w1h)[i] = h;
        ((us4*)w1l)[i] = ll;
    } else if (blk < 512) {
        const int i = (blk - 256) * 256 + tid;
        f32x4 v = ((const f32x4*)W2)[i];
        us4 h;
#pragma unroll
        for (int e = 0; e < 4; ++e) h[e] = f2h(v[e]);
        ((us4*)w2f)[i] = h;
    } else if (blk < 768) {
        const int i = (blk - 512) * 256 + tid;
        f32x4 v = ((const f32x4*)Mw1)[i];
        us4 h;
#pragma unroll
        for (int e = 0; e < 4; ++e) h[e] = f2h(v[e]);
        ((us4*)m1f)[i] = h;
    } else if (blk < 896) {
        const int w = tid >> 6, l = tid & 63;
        const int j = (blk - 768) * 4 + w;
        const float* row = W1 + (size_t)j * 512;
        float a = 0.f;
#pragma unroll
        for (int i = 0; i < 8; ++i) a += row[l + i * 64] * bfv[l + i * 64];
#pragma unroll
        for (int off = 32; off >= 1; off >>= 1) a += __shfl_xor(a, off);
        if (l == 0) bc[j] = a + b1[j];
    } else if (blk < 898) {
        const int j = (blk - 896) * 256 + tid;  // 0..511
        float a = 0.f;
        for (int i = 0; i < 32; ++i) a += Mw3[i] * Mw2[(size_t)i * 512 + j];
        uc[j] = a;
        if (j == 0) {
            float c = Mb3[0];
            for (int i = 0; i < 32; ++i) c += Mw3[i] * Mb2[i];
            uc[512] = c;
        }
    } else {
        const int idx = blk - 898;          // 0..511
        const int k0 = (idx & 31) * 32;     // Wf col tile
        const int i0 = (idx >> 5) * 32;     // Wf row tile
        const int tx = tid & 31;
        const int ty = tid >> 5;  // 0..7
#pragma unroll
        for (int e = 0; e < 4; ++e) {
            const int i = ty + e * 8;
            tile[i][tx] = Wf[(size_t)(i0 + i) * 1024 + k0 + tx];
        }
        __syncthreads();
#pragma unroll
        for (int e = 0; e < 4; ++e) {
            const int kk = ty + e * 8;
            const float v = tile[tx][kk];
            const unsigned short h = f2bf(v);
            wfTh[(size_t)(k0 + kk) * 512 + i0 + tx] = h;
            wfTl[(size_t)(k0 + kk) * 512 + i0 + tx] = f2bf(v - bf2f(h));
        }
    }
}

// ---------------------------------------------------------------------------
// Tail: pre[row] = sum_{s<8} part[s][row] + c; top-17 on pre (sigmoid
// monotonic), mean of sigmoid(selected). One wave per clip.
// ---------------------------------------------------------------------------
__global__ __launch_bounds__(64) void tail_topk(const float* __restrict__ part,
                                                const float* __restrict__ uc,
                                                float* __restrict__ out) {
    const int b = blockIdx.x;
    const int lane = threadIdx.x;
    const float c = uc[512];
    float v[4];
#pragma unroll
    for (int i = 0; i < 4; ++i) {
        const int row = b * T_ + lane + i * 64;
        float a = 0.f;
#pragma unroll
        for (int s = 0; s < 8; ++s) a += part[(size_t)s * M_ + row];
        v[i] = a + c;
    }
    float sum = 0.f;
    for (int iter = 0; iter < 17; ++iter) {
        float mv = v[0];
        int mslot = 0;
#pragma unroll
        for (int i = 1; i < 4; ++i)
            if (v[i] > mv) { mv = v[i]; mslot = i; }
        float bv = mv;
        int bl = lane, bs = mslot;
#pragma unroll
        for (int off = 32; off >= 1; off >>= 1) {
            const float ov = __shfl_xor(bv, off);
            const int ol = __shfl_xor(bl, off);
            const int os = __shfl_xor(bs, off);
            if (ov > bv || (ov == bv && ol < bl)) { bv = ov; bl = ol; bs = os; }
        }
        sum += 1.f / (1.f + expf(-bv));
        if (lane == bl) v[bs] = -1e30f;
    }
    if (lane == 0) out[b] = sum * (1.f / 17.f);
}

// ---------------------------------------------------------------------------
// Orchestration (6 launches):
//   prep_small (weights + Wf transpose)
//   wcf   <- gemm_bf16_wc(W1 planes @ WfT^T)      [BK=64 dbuf]
//   sbuf1 <- gemm_scan<1>(f_f(f32) @ wcf^T + bc)  [16-wave, 128N tile]
//   sbuf2 <- gemm_scan<0>(sbuf1 @ w2f^T + b2)     [16-wave, 128N tile]
//   part  <- gemm_mil(sbuf2 @ m1f^T + Mb1)        [16-wave, 128N, MIL fused]
//   out   <- tail_topk(part)
// ---------------------------------------------------------------------------
extern "C" void kernel_launch(void* const* d_in, const int* in_sizes, int n_in,
                              void* d_out, int out_size, void* d_ws, size_t ws_size,
                              hipStream_t stream) {
    const float* f_f = (const float*)d_in[0];
    const float* Wf  = (const float*)d_in[2];
    const float* bf  = (const float*)d_in[3];
    const float* W1  = (const float*)d_in[4];
    const float* b1  = (const float*)d_in[5];
    const float* W2  = (const float*)d_in[6];
    const float* b2  = (const float*)d_in[7];
    const float* Mw1 = (const float*)d_in[8];
    const float* Mb1 = (const float*)d_in[9];
    const float* Mw2 = (const float*)d_in[10];
    const float* Mb2 = (const float*)d_in[11];
    const float* Mw3 = (const float*)d_in[12];
    const float* Mb3 = (const float*)d_in[13];
    float* out = (float*)d_out;

    char* ws = (char*)d_ws;
    const size_t NE = (size_t)M_ * H_;   // 8.39M elems
    ushort_t* sbuf1 = (ushort_t*)ws;                     // f16 spikes 1
    ushort_t* sbuf2 = sbuf1 + NE;                        // f16 spikes 2
    ushort_t* w1h = sbuf2 + NE;                          // bf16 (wc input)
    ushort_t* w1l = w1h + 262144;
    ushort_t* w2f = w1l + 262144;                        // f16 single
    ushort_t* m1f = w2f + 262144;                        // f16 single
    ushort_t* wfTh = m1f + 262144;                       // bf16 [1024,512]
    ushort_t* wfTl = wfTh + 524288;
    ushort_t* wcf = wfTl + 524288;                       // f16 [512,1024]
    float* bc = (float*)(wcf + 524288);
    float* uc = bc + 512;                                // u[512] + c
    float* part = uc + 513 + 63;                         // [8][16384] f32

    const dim3 blk(256);

    prep_small<<<dim3(1410), blk, 0, stream>>>(W1, W2, Mw1, bf, b1, Mw2, Mb2,
                                               Mw3, Mb3, Wf, w1h, w1l, w2f,
                                               m1f, bc, uc, wfTh, wfTl);

    // Wc = W1 @ Wf -> f16 [512,1024]
    gemm_bf16_wc<<<dim3(8, 4), blk, 0, stream>>>(w1h, w1l, wfTh, wfTl, wcf,
                                                 1024, 512);
    // x1 = f_f @ Wc^T + bc, fused scan1 -> sbuf1 (f32 A, in-kernel convert)
    gemm_scan<1><<<dim3(4, 64), dim3(1024), 0, stream>>>(f_f, wcf, bc, sbuf1,
                                                         1024);
    // x2 = sbuf1 @ W2^T + b2, fused scan2 -> sbuf2
    gemm_scan<0><<<dim3(4, 64), dim3(1024), 0, stream>>>(sbuf1, w2f, b2, sbuf2,
                                                         512);
    // z-GEMM with fused MIL head -> part[8][M]
    gemm_mil<<<dim3(4, 64), dim3(1024), 0, stream>>>(sbuf2, m1f, Mb1, uc, part,
                                                     512, 512);
    tail_topk<<<dim3(B_), dim3(64), 0, stream>>>(part, uc, out);
}